// Round 11
// baseline (226.412 us; speedup 1.0000x reference)
//
#include <hip/hip_runtime.h>
#include <hip/hip_bf16.h>

// RecognitionLattice: RNN-T style lattice loss.
// k_prep (coalesced Wf transpose + Wo shuffle + cemb gather) -> k_fproj GEMM
// -> k_joint: h=tanh(fproj+cemb) @ Wo (poly tanh), 768-thr block, 64x48 wave
//    tile, <=85 regs -> 6 waves/SIMD, dbuf single-barrier K-loop, fused LSE
// -> k_compact: parallel depth-4 semiring compaction -> Dg
// -> k_dpser: 1 wave/batch serial chain, 128 banded-lse5 steps, 8-deep reg ring.

#define BB 4
#define TT 512
#define UU 96
#define FF 512
#define HH 512
#define VV 256
#define NV (VV + 1)    // 257 vocab incl. blank
#define NU (UU + 1)    // 97 lattice rows per t
#define NP 288         // 18*16 padded N
#define NEG_INF (-1e30f)
#define LOG2E 1.4426950408889634f
#define LN2 0.6931471805599453f
#define NG 128         // groups of 4 t-steps
#define GSTRIDE 520    // 5*104 floats per group operator

typedef __bf16 bf16;
typedef __bf16 bf16x8 __attribute__((ext_vector_type(8)));
typedef float f32x4 __attribute__((ext_vector_type(4)));

// tanh via clamped odd polynomial: no transcendentals. Max err ~0.007 on
// [-2,2]; |x|>2 (4.4 sigma, ~1e-5 of inputs) clamps to +-0.9641.
__device__ __forceinline__ float fast_tanh(float x) {
    x = fminf(fmaxf(x, -2.0f), 2.0f);
    float y = x * x;
    float p = __builtin_fmaf(y, -0.0067528f, 0.0700672f);
    p = __builtin_fmaf(y, p, -0.301720f);
    p = __builtin_fmaf(y, p, 1.0f);
    return x * p;
}

// base-2 log-domain ops (inputs/outputs already scaled by log2(e))
__device__ __forceinline__ float lae2(float x, float y) {
    float m = fmaxf(x, y);
    float d = fminf(x, y) - m;
    return m + __builtin_amdgcn_logf(1.0f + __builtin_amdgcn_exp2f(d));
}

__device__ __forceinline__ float lse3_2(float x, float y, float z) {
    float m = fmaxf(fmaxf(x, y), z);
    float s = __builtin_amdgcn_exp2f(x - m) + __builtin_amdgcn_exp2f(y - m) +
              __builtin_amdgcn_exp2f(z - m);
    return m + __builtin_amdgcn_logf(s);
}

__device__ __forceinline__ float lse5_2(float a, float b, float c, float d, float e) {
    float m = fmaxf(fmaxf(fmaxf(a, b), fmaxf(c, d)), e);
    float s = __builtin_amdgcn_exp2f(a - m) + __builtin_amdgcn_exp2f(b - m) +
              __builtin_amdgcn_exp2f(c - m) + __builtin_amdgcn_exp2f(d - m) +
              __builtin_amdgcn_exp2f(e - m);
    return m + __builtin_amdgcn_logf(s);
}

__device__ __forceinline__ void async_copy16(const void* g, void* l) {
    __builtin_amdgcn_global_load_lds(
        (const __attribute__((address_space(1))) unsigned int*)g,
        (__attribute__((address_space(3))) unsigned int*)l, 16, 0, 0);
}

// ---- fused prep ----
__global__ void k_prep(const float* __restrict__ Wf, const float* __restrict__ Wo,
                       const float* __restrict__ E, const int* __restrict__ labels,
                       bf16* __restrict__ Wf_t, bf16* __restrict__ Wo_s,
                       bf16* __restrict__ cemb) {
    __shared__ float tile[64][65];
    const int blk = blockIdx.x;
    const int tid = threadIdx.x;
    if (blk < 64) {
        const int k0 = (blk >> 3) * 64, n0 = (blk & 7) * 64;
        const int rb = tid >> 6, col = tid & 63;
#pragma unroll
        for (int p = 0; p < 16; ++p) {
            int row = p * 4 + rb;
            tile[row][col] = Wf[(size_t)(k0 + row) * HH + n0 + col];
        }
        __syncthreads();
        const int rowp = tid & 63, cb = tid >> 6;
#pragma unroll
        for (int p = 0; p < 16; ++p) {
            int colp = p * 4 + cb;
            Wf_t[(size_t)(n0 + colp) * FF + k0 + rowp] = (bf16)tile[rowp][colp];
        }
    } else if (blk < 136) {
        int idx = (blk - 64) * 256 + tid;  // 0..18431
        int n = idx % NP;
        int rest = idx / NP;
        int kg = rest & 3;
        int k32 = rest >> 2;
        bf16x8 v;
#pragma unroll
        for (int e = 0; e < 8; ++e) {
            int k = k32 * 32 + kg * 8 + e;
            v[e] = (n < NV) ? (bf16)Wo[k * NV + n] : (bf16)0.f;
        }
        *(bf16x8*)&Wo_s[(size_t)idx * 8] = v;
    } else {
        int u = blk - 136;  // 0..96
        for (int b = 0; b < BB; ++b) {
            int ctx = (u == 0) ? 0 : labels[b * UU + (u - 1)];
            const float* src = E + (size_t)ctx * HH;
            bf16* dst = cemb + ((size_t)b * NU + u) * HH;
            for (int i = tid; i < HH; i += 256) dst[i] = (bf16)src[i];
        }
    }
}

// ---- fproj = frames @ Wf  (bf16 MFMA, bf16 out) ----
__global__ __launch_bounds__(256, 2) void k_fproj(
    const float* __restrict__ frames, const bf16* __restrict__ Wf_t,
    bf16* __restrict__ fproj) {
    __shared__ bf16 Alds[64 * 40];
    __shared__ bf16 Blds[64 * 40];
    const int tid = threadIdx.x;
    const int r0 = blockIdx.x * 64;
    const int n0 = blockIdx.y * 64;
    const int lane = tid & 63, w = tid >> 6;
    const int c = lane & 15, g = lane >> 4;

    const int srow = tid >> 2, sko = (tid & 3) * 8;
    const float* fptr = frames + (size_t)(r0 + srow) * FF + sko;
    const bf16* wptr = Wf_t + (size_t)(n0 + srow) * FF + sko;

    f32x4 acc[4];
#pragma unroll
    for (int j = 0; j < 4; ++j) acc[j] = (f32x4){0.f, 0.f, 0.f, 0.f};

    for (int kt = 0; kt < FF; kt += 32) {
        float4 f1 = *(const float4*)(fptr + kt);
        float4 f2 = *(const float4*)(fptr + kt + 4);
        bf16x8 av = {(bf16)f1.x, (bf16)f1.y, (bf16)f1.z, (bf16)f1.w,
                     (bf16)f2.x, (bf16)f2.y, (bf16)f2.z, (bf16)f2.w};
        *(bf16x8*)&Alds[srow * 40 + sko] = av;
        *(bf16x8*)&Blds[srow * 40 + sko] = *(const bf16x8*)(wptr + kt);
        __syncthreads();
        const int m = w * 16;
        bf16x8 af = *(const bf16x8*)&Alds[(m + c) * 40 + g * 8];
#pragma unroll
        for (int j = 0; j < 4; ++j) {
            bf16x8 bv = *(const bf16x8*)&Blds[(j * 16 + c) * 40 + g * 8];
            acc[j] = __builtin_amdgcn_mfma_f32_16x16x32_bf16(af, bv, acc[j], 0, 0, 0);
        }
        __syncthreads();
    }
    const int m = w * 16;
#pragma unroll
    for (int j = 0; j < 4; ++j)
#pragma unroll
        for (int r = 0; r < 4; ++r)
            fproj[(size_t)(r0 + m + g * 4 + r) * HH + n0 + j * 16 + c] = (bf16)acc[j][r];
}

// ---- joint: logits = tanh(fproj[t]+cemb[u]) @ Wo, fused log_softmax extract ----
// grid (388, B), block 768 = 12 waves (2 M-slots x 6 N-slots), wave tile 64x48.
// acc[4][3]=48 AGPR; launch_bounds(768,6) caps regs at 85 -> 6 waves/SIMD,
// 24 waves/CU (2 blocks co-resident). Staging by threads < 512 (1 task each).
__global__ __launch_bounds__(768, 6) void k_joint(
    const bf16* __restrict__ fproj, const bf16* __restrict__ cemb,
    const bf16* __restrict__ Wo_s, const int* __restrict__ labels,
    const int* __restrict__ num_frames, float* __restrict__ cl_arr) {
    __shared__ bf16 A_s[2][4 * 1040];   // 2 x 8320 B, kg-plane stride 1040
    __shared__ bf16 B_s[2][18 * 512];   // 2 x 18432 B, flat [kg][n][8]
    __shared__ float red[8 * 128];      // pmax[6][128], then psum below
    __shared__ float red2[8 * 128];

    const int tid = threadIdx.x;
    const int b = blockIdx.y;
    const int r0 = blockIdx.x * 128;
    const int nf = num_frames[b];
    if (r0 / NU >= nf) return;  // whole tile beyond active frames: outputs unused

    const int lane = tid & 63, w = tid >> 6;
    const int wm = w & 1, wn = w >> 1;   // M-slot (64 rows), N-slot (48 cols)
    const int c = lane & 15, g = lane >> 4;

    // A-staging: 128 rows x 4 kg = 512 tasks, threads < 512 take one each.
    const bool stager = tid < 512;
    const int arow = tid >> 2, akg = tid & 3;
    const int gr = r0 + arow;
    const int at = gr / NU, au = gr - at * NU;
    const bf16* pf = fproj + ((size_t)(b * TT + at)) * HH + akg * 8;
    const bf16* pc = cemb + ((size_t)(b * NU + au)) * HH + akg * 8;
    const int sdst = akg * 1040 + arow * 8;
    const bf16* wsrc = Wo_s + (size_t)lane * 8;

    f32x4 acc[4][3];
#pragma unroll
    for (int mt = 0; mt < 4; ++mt)
#pragma unroll
        for (int j = 0; j < 3; ++j) acc[mt][j] = (f32x4){0.f, 0.f, 0.f, 0.f};

    const int aBase = g * 1040 + (wm * 64 + c) * 8;
    const int bBase = g * 2304 + (wn * 48 + c) * 8;

    // ---- prologue: stage k32=0 into buffer 0 ----
    {
        for (int ch = w; ch < 18; ch += 12)
            async_copy16(wsrc + ch * 512, &B_s[0][ch * 512 + lane * 8]);
        if (stager) {
            bf16x8 fv = *(const bf16x8*)pf;
            bf16x8 cv = *(const bf16x8*)pc;
            bf16x8 av;
#pragma unroll
            for (int e = 0; e < 8; ++e)
                av[e] = (bf16)fast_tanh((float)fv[e] + (float)cv[e]);
            *(bf16x8*)&A_s[0][sdst] = av;
        }
        __syncthreads();
    }

    // ---- main loop: one barrier per k32 ----
    for (int i = 0; i < 16; ++i) {
        const int cur = i & 1, nxt = cur ^ 1;
        bf16x8 bv[3];
#pragma unroll
        for (int j = 0; j < 3; ++j)
            bv[j] = *(const bf16x8*)&B_s[cur][bBase + j * 128];
#pragma unroll
        for (int mt = 0; mt < 4; ++mt) {
            bf16x8 af = *(const bf16x8*)&A_s[cur][aBase + mt * 128];
#pragma unroll
            for (int j = 0; j < 3; ++j)
                acc[mt][j] = __builtin_amdgcn_mfma_f32_16x16x32_bf16(af, bv[j], acc[mt][j], 0, 0, 0);
        }
        if (i < 15) {
            const int kt = (i + 1) * 32;
            const bf16* wk = wsrc + (size_t)(i + 1) * 9216;
            for (int ch = w; ch < 18; ch += 12)
                async_copy16(wk + ch * 512, &B_s[nxt][ch * 512 + lane * 8]);
            if (stager) {
                bf16x8 fv2 = *(const bf16x8*)(pf + kt);
                bf16x8 cv2 = *(const bf16x8*)(pc + kt);
                bf16x8 av;
#pragma unroll
                for (int e = 0; e < 8; ++e)
                    av[e] = (bf16)fast_tanh((float)fv2[e] + (float)cv2[e]);
                *(bf16x8*)&A_s[nxt][sdst] = av;
            }
        }
        __syncthreads();
    }

    // epilogue: per-wave partial lse over owned 48 cols, 6-way combine in LDS
    float* pmax = red;          // [6][128]
    float* pblank = red + 768;  // [128]
    float* psum = red2;         // [6][128]
    float* plex = red2 + 768;   // [128]

#pragma unroll
    for (int mt = 0; mt < 4; ++mt) {
#pragma unroll
        for (int r = 0; r < 4; ++r) {
            int row_in = wm * 64 + mt * 16 + g * 4 + r;
            int grr = r0 + row_in;
            int u = grr - (grr / NU) * NU;

            float mx = NEG_INF;
#pragma unroll
            for (int j = 0; j < 3; ++j) {
                int col = wn * 48 + j * 16 + c;
                if (col < NV) mx = fmaxf(mx, acc[mt][j][r]);
            }
#pragma unroll
            for (int s = 1; s < 16; s <<= 1) mx = fmaxf(mx, __shfl_xor(mx, s));
            float sum = 0.f;
#pragma unroll
            for (int j = 0; j < 3; ++j) {
                int col = wn * 48 + j * 16 + c;
                if (col < NV) sum += __expf(acc[mt][j][r] - mx);
            }
#pragma unroll
            for (int s = 1; s < 16; s <<= 1) sum += __shfl_xor(sum, s);

            int L = (u < UU) ? labels[b * UU + u] : -1;  // 1..256 or -1
            int lc = L - wn * 48;
            bool own = (lc >= 0) && (lc < 48);
            int src = (lane & 48) | (lc & 15);
            int jl = lc >> 4;
            float lexv = 0.f;
#pragma unroll
            for (int j = 0; j < 3; ++j) {
                float cand = __shfl(acc[mt][j][r], src);
                if (j == jl) lexv = cand;
            }
            float blankv = __shfl(acc[mt][0][r], lane & 48);  // col 0 (wn==0)

            if (c == 0) {
                pmax[wn * 128 + row_in] = mx;
                psum[wn * 128 + row_in] = sum;
                if (wn == 0) pblank[row_in] = blankv;
                if (own) plex[row_in] = lexv;
            }
        }
    }
    __syncthreads();
    if (tid < 128) {
        int grr = r0 + tid;
        int t = grr / NU, u = grr - t * NU;
        float mx = NEG_INF;
#pragma unroll
        for (int s = 0; s < 6; ++s) mx = fmaxf(mx, pmax[s * 128 + tid]);
        float sm = 0.f;
#pragma unroll
        for (int s = 0; s < 6; ++s)
            sm += psum[s * 128 + tid] * __expf(pmax[s * 128 + tid] - mx);
        float lse = mx + __logf(sm);
        float2 v;
        v.x = pblank[tid] - lse;
        v.y = (u < UU) ? (plex[tid] - lse) : 0.f;
        *(float2*)&cl_arr[(((size_t)b * TT + t) * NU + u) * 2] = v;
    }
}

// ---- parallel depth-4 compaction: grid (NG, BB), block 128 (one thread per u).
__global__ __launch_bounds__(128) void k_compact(
    const float* __restrict__ cl, const int* __restrict__ num_frames,
    float* __restrict__ Dg) {
    const int g = blockIdx.x;
    const int b = blockIdx.y;
    const int u = threadIdx.x;
    if (u >= NU) return;
    const int nf = num_frames[b];
    const float2* P = (const float2*)(cl + (size_t)b * TT * NU * 2);

    auto fetch = [&](int t, int uu, float& bb, float& ll) {
        if (uu <= UU) {
            float2 z = P[t * NU + uu];
            bool act = t < nf;
            bb = act ? z.x * LOG2E : 0.f;
            ll = (act && uu < UU) ? z.y * LOG2E : NEG_INF;
        } else {
            bb = NEG_INF;
            ll = NEG_INF;
        }
    };

    const int t0 = g * 4;
    float b0, l0, b1u, l1u, b1u1, l1u1;
    fetch(t0, u, b0, l0);
    fetch(t0 + 1, u, b1u, l1u);
    fetch(t0 + 1, u + 1, b1u1, l1u1);
    float A0 = b0 + b1u;
    float A1 = lae2(l0 + b1u1, b0 + l1u);
    float A2 = l0 + l1u1;
    float B0[3], B1[3], B2[3];
#pragma unroll
    for (int j = 0; j < 3; ++j) {
        float b2v, l2v, b3v, l3v, b3n, l3n;
        fetch(t0 + 2, u + j, b2v, l2v);
        fetch(t0 + 3, u + j, b3v, l3v);
        fetch(t0 + 3, u + j + 1, b3n, l3n);
        B0[j] = b2v + b3v;
        B1[j] = lae2(l2v + b3n, b2v + l3v);
        B2[j] = l2v + l3n;
    }
    float* d = Dg + ((size_t)b * NG + g) * GSTRIDE;
    d[u] = A0 + B0[0];
    d[104 + u] = lae2(A1 + B0[1], A0 + B1[0]);
    d[208 + u] = lse3_2(A2 + B0[2], A1 + B1[1], A0 + B2[0]);
    d[312 + u] = lae2(A2 + B1[2], A1 + B2[1]);
    d[416 + u] = A2 + B2[2];
}

// ---- serial chain: 1 wave per batch, 128 banded-lse5 steps, 8-deep reg ring.
__global__ __launch_bounds__(64) void k_dpser(
    const float* __restrict__ Dg, const int* __restrict__ num_labels,
    float* __restrict__ out) {
    const int b = blockIdx.x;
    const int lane = threadIdx.x;
    const float* D = Dg + (size_t)b * NG * GSTRIDE;
    const int lo_u = lane;
    const int hi_u = 64 + ((lane < 33) ? lane : 0);

    float a_lo = (lane == 0) ? 0.f : NEG_INF;  // alpha[u=lane] (base-2)
    float a_hi = NEG_INF;                      // alpha[u=64+lane], lane<33

    constexpr int R = 8;
    float blo[R][5], bhi[R][5];
#pragma unroll
    for (int g = 0; g < R; ++g)
#pragma unroll
        for (int k = 0; k < 5; ++k) {
            blo[g][k] = D[g * GSTRIDE + k * 104 + lo_u];
            bhi[g][k] = D[g * GSTRIDE + k * 104 + hi_u];
        }

#pragma unroll 8
    for (int g = 0; g < NG; ++g) {
        const int slot = g & (R - 1);
        float el[5], eh[5];
#pragma unroll
        for (int k = 0; k < 5; ++k) {
            el[k] = a_lo + blo[slot][k];
            eh[k] = a_hi + bhi[slot][k];
        }
        const int gp = g + R;
        if (gp < NG) {
#pragma unroll
            for (int k = 0; k < 5; ++k) {
                blo[slot][k] = D[gp * GSTRIDE + k * 104 + lo_u];
                bhi[slot][k] = D[gp * GSTRIDE + k * 104 + hi_u];
            }
        }
        float ml[5], mh[5];
        ml[0] = el[0];
        mh[0] = eh[0];
#pragma unroll
        for (int k = 1; k < 5; ++k) {
            float su = __shfl_up(el[k], k);
            ml[k] = (lane >= k) ? su : NEG_INF;
            float sh = __shfl_up(eh[k], k);
            float xl = __shfl(el[k], 64 - k + lane);  // lo lanes 63..64-k
            mh[k] = (lane >= k) ? sh : xl;
        }
        a_lo = lse5_2(ml[0], ml[1], ml[2], ml[3], ml[4]);
        float nh = lse5_2(mh[0], mh[1], mh[2], mh[3], mh[4]);
        if (lane < 33) a_hi = nh;
    }

    const int nl = num_labels[b];
    float res = (nl < 64) ? __shfl(a_lo, nl) : __shfl(a_hi, nl - 64);
    if (lane == 0) out[b] = -res * LN2;  // back to natural-log domain
}

extern "C" void kernel_launch(void* const* d_in, const int* in_sizes, int n_in,
                              void* d_out, int out_size, void* d_ws, size_t ws_size,
                              hipStream_t stream) {
    const float* frames = (const float*)d_in[0];
    const int* num_frames = (const int*)d_in[1];
    const int* labels = (const int*)d_in[2];
    const int* num_labels = (const int*)d_in[3];
    const float* Wf = (const float*)d_in[4];
    const float* E = (const float*)d_in[5];
    const float* Wo = (const float*)d_in[6];
    float* out = (float*)d_out;

    char* ws = (char*)d_ws;
    size_t off = 0;
    bf16* Wf_t = (bf16*)(ws + off); off += (size_t)HH * FF * 2;               // 512 KiB
    bf16* Wo_s = (bf16*)(ws + off); off += (size_t)16 * 9216 * 2;             // 288 KiB
    bf16* cemb = (bf16*)(ws + off); off += (size_t)BB * NU * HH * 2;          // 388 KiB
    off = (off + 255) & ~(size_t)255;
    bf16* fproj = (bf16*)(ws + off); off += (size_t)BB * TT * HH * 2;         // 2 MiB
    off = (off + 255) & ~(size_t)255;
    float* cl_arr = (float*)(ws + off); off += (size_t)BB * TT * NU * 2 * 4;  // 1.52 MiB
    off = (off + 255) & ~(size_t)255;
    float* Dg = (float*)(ws + off); off += (size_t)BB * NG * GSTRIDE * 4;     // 1.02 MiB

    hipLaunchKernelGGL(k_prep, dim3(233), dim3(256), 0, stream,
                       Wf, Wo, E, labels, Wf_t, Wo_s, cemb);
    hipLaunchKernelGGL(k_fproj, dim3((BB * TT) / 64, HH / 64), dim3(256), 0, stream,
                       frames, Wf_t, fproj);
    hipLaunchKernelGGL(k_joint, dim3((TT * NU) / 128, BB), dim3(768), 0, stream,
                       fproj, cemb, Wo_s, labels, num_frames, cl_arr);
    hipLaunchKernelGGL(k_compact, dim3(NG, BB), dim3(128), 0, stream,
                       cl_arr, num_frames, Dg);
    hipLaunchKernelGGL(k_dpser, dim3(BB), dim3(64), 0, stream,
                       Dg, num_labels, out);
}

// Round 12
// 211.330 us; speedup vs baseline: 1.0714x; 1.0714x over previous
//
#include <hip/hip_runtime.h>
#include <hip/hip_bf16.h>

// RecognitionLattice: RNN-T style lattice loss.
// k_front: fproj GEMM (direct fp32-Wf transpose staging) + Wo shuffle + cemb
//          gather as independent block ranges of ONE launch
// -> k_joint: h=tanh(fproj+cemb) @ Wo, 512-thr block, 32x144 wave tile,
//    dbuf single-barrier K-loop, fused LSE  [round-10 verified config]
// -> k_compact: parallel depth-4 semiring compaction -> Dg
// -> k_dpser: 1 wave/batch serial chain, 128 banded-lse5 steps, 8-deep reg ring.

#define BB 4
#define TT 512
#define UU 96
#define FF 512
#define HH 512
#define VV 256
#define NV (VV + 1)    // 257 vocab incl. blank
#define NU (UU + 1)    // 97 lattice rows per t
#define NP 288         // 18*16 padded N
#define NEG_INF (-1e30f)
#define LOG2E 1.4426950408889634f
#define LN2 0.6931471805599453f
#define NG 128         // groups of 4 t-steps
#define GSTRIDE 520    // 5*104 floats per group operator

typedef __bf16 bf16;
typedef __bf16 bf16x8 __attribute__((ext_vector_type(8)));
typedef float f32x4 __attribute__((ext_vector_type(4)));

// tanh via clamped odd polynomial: no transcendentals. Max err ~0.007 on
// [-2,2]; |x|>2 (4.4 sigma, ~1e-5 of inputs) clamps to +-0.9641.
__device__ __forceinline__ float fast_tanh(float x) {
    x = fminf(fmaxf(x, -2.0f), 2.0f);
    float y = x * x;
    float p = __builtin_fmaf(y, -0.0067528f, 0.0700672f);
    p = __builtin_fmaf(y, p, -0.301720f);
    p = __builtin_fmaf(y, p, 1.0f);
    return x * p;
}

// base-2 log-domain ops (inputs/outputs already scaled by log2(e))
__device__ __forceinline__ float lae2(float x, float y) {
    float m = fmaxf(x, y);
    float d = fminf(x, y) - m;
    return m + __builtin_amdgcn_logf(1.0f + __builtin_amdgcn_exp2f(d));
}

__device__ __forceinline__ float lse3_2(float x, float y, float z) {
    float m = fmaxf(fmaxf(x, y), z);
    float s = __builtin_amdgcn_exp2f(x - m) + __builtin_amdgcn_exp2f(y - m) +
              __builtin_amdgcn_exp2f(z - m);
    return m + __builtin_amdgcn_logf(s);
}

__device__ __forceinline__ float lse5_2(float a, float b, float c, float d, float e) {
    float m = fmaxf(fmaxf(fmaxf(a, b), fmaxf(c, d)), e);
    float s = __builtin_amdgcn_exp2f(a - m) + __builtin_amdgcn_exp2f(b - m) +
              __builtin_amdgcn_exp2f(c - m) + __builtin_amdgcn_exp2f(d - m) +
              __builtin_amdgcn_exp2f(e - m);
    return m + __builtin_amdgcn_logf(s);
}

__device__ __forceinline__ void async_copy16(const void* g, void* l) {
    __builtin_amdgcn_global_load_lds(
        (const __attribute__((address_space(1))) unsigned int*)g,
        (__attribute__((address_space(3))) unsigned int*)l, 16, 0, 0);
}

// ---- front: fproj GEMM + Wo shuffle + cemb gather (independent block ranges)
// blk [0,256):   fproj tile: r0=(blk&31)*64, n0=(blk>>5)*64. B staged DIRECTLY
//                from fp32 Wf with on-the-fly transpose (no Wf_t buffer).
// blk [256,328): Wo_s[k32][kg][n][8] = bf16(Wo[k32*32+kg*8+e][n]) (n<257 else 0)
// blk [328,425): cemb[b][u][:] = bf16(E[ctx(b,u)][:])
__global__ __launch_bounds__(256, 2) void k_front(
    const float* __restrict__ frames, const float* __restrict__ Wf,
    const float* __restrict__ Wo, const float* __restrict__ E,
    const int* __restrict__ labels, bf16* __restrict__ fproj,
    bf16* __restrict__ Wo_s, bf16* __restrict__ cemb) {
    __shared__ bf16 Alds[64 * 40];
    __shared__ bf16 Blds[64 * 40];
    const int blk = blockIdx.x;
    const int tid = threadIdx.x;

    if (blk < 256) {
        const int r0 = (blk & 31) * 64;
        const int n0 = (blk >> 5) * 64;
        const int lane = tid & 63, w = tid >> 6;
        const int c = lane & 15, g = lane >> 4;

        const int srow = tid >> 2, sko = (tid & 3) * 8;
        const float* fptr = frames + (size_t)(r0 + srow) * FF + sko;
        const int q = tid >> 6, c64 = tid & 63;  // B-transpose staging coords

        f32x4 acc[4];
#pragma unroll
        for (int j = 0; j < 4; ++j) acc[j] = (f32x4){0.f, 0.f, 0.f, 0.f};

        for (int kt = 0; kt < FF; kt += 32) {
            float4 f1 = *(const float4*)(fptr + kt);
            float4 f2 = *(const float4*)(fptr + kt + 4);
            bf16x8 av = {(bf16)f1.x, (bf16)f1.y, (bf16)f1.z, (bf16)f1.w,
                         (bf16)f2.x, (bf16)f2.y, (bf16)f2.z, (bf16)f2.w};
            *(bf16x8*)&Alds[srow * 40 + sko] = av;
            // B: Blds[n][k] = Wf[kt+k][n0+n]; coalesced row reads, transpose write
#pragma unroll
            for (int p = 0; p < 8; ++p) {
                float v = Wf[(size_t)(kt + q * 8 + p) * HH + n0 + c64];
                Blds[c64 * 40 + q * 8 + p] = (bf16)v;
            }
            __syncthreads();
            const int m = w * 16;
            bf16x8 af = *(const bf16x8*)&Alds[(m + c) * 40 + g * 8];
#pragma unroll
            for (int j = 0; j < 4; ++j) {
                bf16x8 bv = *(const bf16x8*)&Blds[(j * 16 + c) * 40 + g * 8];
                acc[j] = __builtin_amdgcn_mfma_f32_16x16x32_bf16(af, bv, acc[j], 0, 0, 0);
            }
            __syncthreads();
        }
        const int m = w * 16;
#pragma unroll
        for (int j = 0; j < 4; ++j)
#pragma unroll
            for (int r = 0; r < 4; ++r)
                fproj[(size_t)(r0 + m + g * 4 + r) * HH + n0 + j * 16 + c] = (bf16)acc[j][r];
    } else if (blk < 328) {
        int idx = (blk - 256) * 256 + tid;  // 0..18431
        int n = idx % NP;
        int rest = idx / NP;
        int kg = rest & 3;
        int k32 = rest >> 2;
        bf16x8 v;
#pragma unroll
        for (int e = 0; e < 8; ++e) {
            int k = k32 * 32 + kg * 8 + e;
            v[e] = (n < NV) ? (bf16)Wo[k * NV + n] : (bf16)0.f;
        }
        *(bf16x8*)&Wo_s[(size_t)idx * 8] = v;
    } else {
        int u = blk - 328;  // 0..96
        for (int b = 0; b < BB; ++b) {
            int ctx = (u == 0) ? 0 : labels[b * UU + (u - 1)];
            const float* src = E + (size_t)ctx * HH;
            bf16* dst = cemb + ((size_t)b * NU + u) * HH;
            for (int i = tid; i < HH; i += 256) dst[i] = (bf16)src[i];
        }
    }
}

// ---- joint: logits = tanh(fproj[t]+cemb[u]) @ Wo, fused log_softmax extract ----
// grid (388, B), block 512 = 8 waves (4 M-slots x 2 N-halves), wave tile 32x144.
// [round-10 verified config: 56 arch + 72 acc regs -> 4 waves/SIMD]
__global__ __launch_bounds__(512, 4) void k_joint(
    const bf16* __restrict__ fproj, const bf16* __restrict__ cemb,
    const bf16* __restrict__ Wo_s, const int* __restrict__ labels,
    const int* __restrict__ num_frames, float* __restrict__ cl_arr) {
    __shared__ bf16 A_s[2][4 * 1040];   // 2 x 8320 B, kg-plane stride 1040 (bank rot)
    __shared__ bf16 B_s[2][18 * 512];   // 2 x 18432 B, flat [kg][n][8]
    __shared__ float red[6 * 128];      // cross-wave LSE combine

    const int tid = threadIdx.x;
    const int b = blockIdx.y;
    const int r0 = blockIdx.x * 128;
    const int nf = num_frames[b];
    if (r0 / NU >= nf) return;  // whole tile beyond active frames: outputs unused

    const int lane = tid & 63, w = tid >> 6;
    const int wm = w & 3, wn = w >> 2;
    const int c = lane & 15, g = lane >> 4;

    // A-staging: 128 rows x 4 kg = 512 tasks, one per thread.
    const int arow = tid >> 2, akg = tid & 3;
    const int gr = r0 + arow;
    const int at = gr / NU, au = gr - at * NU;
    const bf16* pf = fproj + ((size_t)(b * TT + at)) * HH + akg * 8;
    const bf16* pc = cemb + ((size_t)(b * NU + au)) * HH + akg * 8;
    const int sdst = akg * 1040 + arow * 8;
    const bf16* wsrc = Wo_s + (size_t)lane * 8;

    f32x4 acc[2][9];
#pragma unroll
    for (int mt = 0; mt < 2; ++mt)
#pragma unroll
        for (int j = 0; j < 9; ++j) acc[mt][j] = (f32x4){0.f, 0.f, 0.f, 0.f};

    const int aBase = g * 1040 + (wm * 32 + c) * 8;
    const int bBase = g * 2304 + (wn * 144 + c) * 8;

    // ---- prologue: stage k32=0 into buffer 0 ----
    {
        for (int ch = w; ch < 18; ch += 8)
            async_copy16(wsrc + ch * 512, &B_s[0][ch * 512 + lane * 8]);
        bf16x8 fv = *(const bf16x8*)pf;
        bf16x8 cv = *(const bf16x8*)pc;
        bf16x8 av;
#pragma unroll
        for (int e = 0; e < 8; ++e)
            av[e] = (bf16)fast_tanh((float)fv[e] + (float)cv[e]);
        *(bf16x8*)&A_s[0][sdst] = av;
        __syncthreads();
    }

    // ---- main loop: one barrier per k32 ----
    for (int i = 0; i < 16; ++i) {
        const int cur = i & 1, nxt = cur ^ 1;
        bf16x8 af[2];
#pragma unroll
        for (int mt = 0; mt < 2; ++mt)
            af[mt] = *(const bf16x8*)&A_s[cur][aBase + mt * 128];
#pragma unroll
        for (int j = 0; j < 9; ++j) {
            bf16x8 bv = *(const bf16x8*)&B_s[cur][bBase + j * 128];
#pragma unroll
            for (int mt = 0; mt < 2; ++mt)
                acc[mt][j] = __builtin_amdgcn_mfma_f32_16x16x32_bf16(af[mt], bv, acc[mt][j], 0, 0, 0);
        }
        if (i < 15) {
            const int kt = (i + 1) * 32;
            bf16x8 fv2 = *(const bf16x8*)(pf + kt);
            bf16x8 cv2 = *(const bf16x8*)(pc + kt);
            const bf16* wk = wsrc + (size_t)(i + 1) * 9216;
            for (int ch = w; ch < 18; ch += 8)
                async_copy16(wk + ch * 512, &B_s[nxt][ch * 512 + lane * 8]);
            bf16x8 av;
#pragma unroll
            for (int e = 0; e < 8; ++e)
                av[e] = (bf16)fast_tanh((float)fv2[e] + (float)cv2[e]);
            *(bf16x8*)&A_s[nxt][sdst] = av;
        }
        __syncthreads();
    }

    // epilogue: per-wave partial lse over owned 144 cols, cross-wave combine in LDS
    float* pmax0 = red;
    float* pmax1 = red + 128;
    float* psum0 = red + 256;
    float* psum1 = red + 384;
    float* pblank = red + 512;
    float* plex = red + 640;

#pragma unroll
    for (int mt = 0; mt < 2; ++mt) {
#pragma unroll
        for (int r = 0; r < 4; ++r) {
            int row_in = wm * 32 + mt * 16 + g * 4 + r;
            int grr = r0 + row_in;
            int u = grr - (grr / NU) * NU;

            float mx = NEG_INF;
#pragma unroll
            for (int j = 0; j < 9; ++j) {
                int col = wn * 144 + j * 16 + c;
                if (col < NV) mx = fmaxf(mx, acc[mt][j][r]);
            }
#pragma unroll
            for (int s = 1; s < 16; s <<= 1) mx = fmaxf(mx, __shfl_xor(mx, s));
            float sum = 0.f;
#pragma unroll
            for (int j = 0; j < 9; ++j) {
                int col = wn * 144 + j * 16 + c;
                if (col < NV) sum += __expf(acc[mt][j][r] - mx);
            }
#pragma unroll
            for (int s = 1; s < 16; s <<= 1) sum += __shfl_xor(sum, s);

            int L = (u < UU) ? labels[b * UU + u] : -1;  // 1..256 or -1
            int lc = L - wn * 144;
            bool own = (lc >= 0) && (lc < 144);
            int src = (lane & 48) | (lc & 15);
            int jl = lc >> 4;
            float lexv = 0.f;
#pragma unroll
            for (int j = 0; j < 9; ++j) {
                float cand = __shfl(acc[mt][j][r], src);
                if (j == jl) lexv = cand;
            }
            float blankv = __shfl(acc[mt][0][r], lane & 48);  // col 0 (valid for wn==0)

            if (c == 0) {
                if (wn == 0) {
                    pmax0[row_in] = mx;
                    psum0[row_in] = sum;
                    pblank[row_in] = blankv;
                } else {
                    pmax1[row_in] = mx;
                    psum1[row_in] = sum;
                }
                if (own) plex[row_in] = lexv;
            }
        }
    }
    __syncthreads();
    if (tid < 128) {
        int grr = r0 + tid;
        int t = grr / NU, u = grr - t * NU;
        float m0 = pmax0[tid], m1 = pmax1[tid];
        float mx = fmaxf(m0, m1);
        float s = psum0[tid] * __expf(m0 - mx) + psum1[tid] * __expf(m1 - mx);
        float lse = mx + __logf(s);
        float2 v;
        v.x = pblank[tid] - lse;
        v.y = (u < UU) ? (plex[tid] - lse) : 0.f;
        *(float2*)&cl_arr[(((size_t)b * TT + t) * NU + u) * 2] = v;
    }
}

// ---- parallel depth-4 compaction: grid (NG, BB), block 128 (one thread per u).
__global__ __launch_bounds__(128) void k_compact(
    const float* __restrict__ cl, const int* __restrict__ num_frames,
    float* __restrict__ Dg) {
    const int g = blockIdx.x;
    const int b = blockIdx.y;
    const int u = threadIdx.x;
    if (u >= NU) return;
    const int nf = num_frames[b];
    const float2* P = (const float2*)(cl + (size_t)b * TT * NU * 2);

    auto fetch = [&](int t, int uu, float& bb, float& ll) {
        if (uu <= UU) {
            float2 z = P[t * NU + uu];
            bool act = t < nf;
            bb = act ? z.x * LOG2E : 0.f;
            ll = (act && uu < UU) ? z.y * LOG2E : NEG_INF;
        } else {
            bb = NEG_INF;
            ll = NEG_INF;
        }
    };

    const int t0 = g * 4;
    float b0, l0, b1u, l1u, b1u1, l1u1;
    fetch(t0, u, b0, l0);
    fetch(t0 + 1, u, b1u, l1u);
    fetch(t0 + 1, u + 1, b1u1, l1u1);
    float A0 = b0 + b1u;
    float A1 = lae2(l0 + b1u1, b0 + l1u);
    float A2 = l0 + l1u1;
    float B0[3], B1[3], B2[3];
#pragma unroll
    for (int j = 0; j < 3; ++j) {
        float b2v, l2v, b3v, l3v, b3n, l3n;
        fetch(t0 + 2, u + j, b2v, l2v);
        fetch(t0 + 3, u + j, b3v, l3v);
        fetch(t0 + 3, u + j + 1, b3n, l3n);
        B0[j] = b2v + b3v;
        B1[j] = lae2(l2v + b3n, b2v + l3v);
        B2[j] = l2v + l3n;
    }
    float* d = Dg + ((size_t)b * NG + g) * GSTRIDE;
    d[u] = A0 + B0[0];
    d[104 + u] = lae2(A1 + B0[1], A0 + B1[0]);
    d[208 + u] = lse3_2(A2 + B0[2], A1 + B1[1], A0 + B2[0]);
    d[312 + u] = lae2(A2 + B1[2], A1 + B2[1]);
    d[416 + u] = A2 + B2[2];
}

// ---- serial chain: 1 wave per batch, 128 banded-lse5 steps, 8-deep reg ring.
__global__ __launch_bounds__(64) void k_dpser(
    const float* __restrict__ Dg, const int* __restrict__ num_labels,
    float* __restrict__ out) {
    const int b = blockIdx.x;
    const int lane = threadIdx.x;
    const float* D = Dg + (size_t)b * NG * GSTRIDE;
    const int lo_u = lane;
    const int hi_u = 64 + ((lane < 33) ? lane : 0);

    float a_lo = (lane == 0) ? 0.f : NEG_INF;  // alpha[u=lane] (base-2)
    float a_hi = NEG_INF;                      // alpha[u=64+lane], lane<33

    constexpr int R = 8;
    float blo[R][5], bhi[R][5];
#pragma unroll
    for (int g = 0; g < R; ++g)
#pragma unroll
        for (int k = 0; k < 5; ++k) {
            blo[g][k] = D[g * GSTRIDE + k * 104 + lo_u];
            bhi[g][k] = D[g * GSTRIDE + k * 104 + hi_u];
        }

#pragma unroll 8
    for (int g = 0; g < NG; ++g) {
        const int slot = g & (R - 1);
        float el[5], eh[5];
#pragma unroll
        for (int k = 0; k < 5; ++k) {
            el[k] = a_lo + blo[slot][k];
            eh[k] = a_hi + bhi[slot][k];
        }
        const int gp = g + R;
        if (gp < NG) {
#pragma unroll
            for (int k = 0; k < 5; ++k) {
                blo[slot][k] = D[gp * GSTRIDE + k * 104 + lo_u];
                bhi[slot][k] = D[gp * GSTRIDE + k * 104 + hi_u];
            }
        }
        float ml[5], mh[5];
        ml[0] = el[0];
        mh[0] = eh[0];
#pragma unroll
        for (int k = 1; k < 5; ++k) {
            float su = __shfl_up(el[k], k);
            ml[k] = (lane >= k) ? su : NEG_INF;
            float sh = __shfl_up(eh[k], k);
            float xl = __shfl(el[k], 64 - k + lane);  // lo lanes 63..64-k
            mh[k] = (lane >= k) ? sh : xl;
        }
        a_lo = lse5_2(ml[0], ml[1], ml[2], ml[3], ml[4]);
        float nh = lse5_2(mh[0], mh[1], mh[2], mh[3], mh[4]);
        if (lane < 33) a_hi = nh;
    }

    const int nl = num_labels[b];
    float res = (nl < 64) ? __shfl(a_lo, nl) : __shfl(a_hi, nl - 64);
    if (lane == 0) out[b] = -res * LN2;  // back to natural-log domain
}

extern "C" void kernel_launch(void* const* d_in, const int* in_sizes, int n_in,
                              void* d_out, int out_size, void* d_ws, size_t ws_size,
                              hipStream_t stream) {
    const float* frames = (const float*)d_in[0];
    const int* num_frames = (const int*)d_in[1];
    const int* labels = (const int*)d_in[2];
    const int* num_labels = (const int*)d_in[3];
    const float* Wf = (const float*)d_in[4];
    const float* E = (const float*)d_in[5];
    const float* Wo = (const float*)d_in[6];
    float* out = (float*)d_out;

    char* ws = (char*)d_ws;
    size_t off = 0;
    bf16* Wo_s = (bf16*)(ws + off); off += (size_t)16 * 9216 * 2;             // 288 KiB
    bf16* cemb = (bf16*)(ws + off); off += (size_t)BB * NU * HH * 2;          // 388 KiB
    off = (off + 255) & ~(size_t)255;
    bf16* fproj = (bf16*)(ws + off); off += (size_t)BB * TT * HH * 2;         // 2 MiB
    off = (off + 255) & ~(size_t)255;
    float* cl_arr = (float*)(ws + off); off += (size_t)BB * TT * NU * 2 * 4;  // 1.52 MiB
    off = (off + 255) & ~(size_t)255;
    float* Dg = (float*)(ws + off); off += (size_t)BB * NG * GSTRIDE * 4;     // 1.02 MiB

    hipLaunchKernelGGL(k_front, dim3(425), dim3(256), 0, stream,
                       frames, Wf, Wo, E, labels, fproj, Wo_s, cemb);
    hipLaunchKernelGGL(k_joint, dim3((TT * NU) / 128, BB), dim3(512), 0, stream,
                       fproj, cemb, Wo_s, labels, num_frames, cl_arr);
    hipLaunchKernelGGL(k_compact, dim3(NG, BB), dim3(128), 0, stream,
                       cl_arr, num_frames, Dg);
    hipLaunchKernelGGL(k_dpser, dim3(BB), dim3(64), 0, stream,
                       Dg, num_labels, out);
}

// Round 13
// 205.059 us; speedup vs baseline: 1.1041x; 1.0306x over previous
//
#include <hip/hip_runtime.h>
#include <hip/hip_bf16.h>

// RecognitionLattice: RNN-T style lattice loss.
// k_front: fproj GEMM (direct fp32-Wf transpose staging) + Wo->fp8 shuffle +
//          cemb gather as independent block ranges of ONE launch
// -> k_joint: h=tanh(fproj+cemb) in fp8 @ Wo_fp8 (mfma 16x16x32_fp8_fp8,
//    halved LDS/staging bytes), dbuf single-barrier K-loop, fused LSE
// -> k_compact: parallel depth-4 semiring compaction -> Dg
// -> k_dpser: 1 wave/batch serial chain, 128 banded-lse5 steps, 8-deep reg ring.

#define BB 4
#define TT 512
#define UU 96
#define FF 512
#define HH 512
#define VV 256
#define NV (VV + 1)    // 257 vocab incl. blank
#define NU (UU + 1)    // 97 lattice rows per t
#define NP 288         // 18*16 padded N
#define NEG_INF (-1e30f)
#define LOG2E 1.4426950408889634f
#define LN2 0.6931471805599453f
#define NG 128         // groups of 4 t-steps
#define GSTRIDE 520    // 5*104 floats per group operator
#define WOSCL 64.0f    // Wo pre-scale into fp8 normal range
#define INVWOSCL 0.015625f

typedef __bf16 bf16;
typedef __bf16 bf16x8 __attribute__((ext_vector_type(8)));
typedef float f32x4 __attribute__((ext_vector_type(4)));

// tanh via clamped odd polynomial: no transcendentals. Max err ~0.007 on
// [-2,2]; |x|>2 (4.4 sigma, ~1e-5 of inputs) clamps to +-0.9641.
__device__ __forceinline__ float fast_tanh(float x) {
    x = fminf(fmaxf(x, -2.0f), 2.0f);
    float y = x * x;
    float p = __builtin_fmaf(y, -0.0067528f, 0.0700672f);
    p = __builtin_fmaf(y, p, -0.301720f);
    p = __builtin_fmaf(y, p, 1.0f);
    return x * p;
}

// pack 8 floats -> 8 fp8 e4m3 in a 64-bit value (HW cvt, RNE)
__device__ __forceinline__ long pack_fp8x8(const float* v) {
    int lo = 0, hi = 0;
    lo = __builtin_amdgcn_cvt_pk_fp8_f32(v[0], v[1], lo, false);
    lo = __builtin_amdgcn_cvt_pk_fp8_f32(v[2], v[3], lo, true);
    hi = __builtin_amdgcn_cvt_pk_fp8_f32(v[4], v[5], hi, false);
    hi = __builtin_amdgcn_cvt_pk_fp8_f32(v[6], v[7], hi, true);
    return (long)(((unsigned long long)(unsigned int)lo) |
                  (((unsigned long long)(unsigned int)hi) << 32));
}

// base-2 log-domain ops (inputs/outputs already scaled by log2(e))
__device__ __forceinline__ float lae2(float x, float y) {
    float m = fmaxf(x, y);
    float d = fminf(x, y) - m;
    return m + __builtin_amdgcn_logf(1.0f + __builtin_amdgcn_exp2f(d));
}

__device__ __forceinline__ float lse3_2(float x, float y, float z) {
    float m = fmaxf(fmaxf(x, y), z);
    float s = __builtin_amdgcn_exp2f(x - m) + __builtin_amdgcn_exp2f(y - m) +
              __builtin_amdgcn_exp2f(z - m);
    return m + __builtin_amdgcn_logf(s);
}

__device__ __forceinline__ float lse5_2(float a, float b, float c, float d, float e) {
    float m = fmaxf(fmaxf(fmaxf(a, b), fmaxf(c, d)), e);
    float s = __builtin_amdgcn_exp2f(a - m) + __builtin_amdgcn_exp2f(b - m) +
              __builtin_amdgcn_exp2f(c - m) + __builtin_amdgcn_exp2f(d - m) +
              __builtin_amdgcn_exp2f(e - m);
    return m + __builtin_amdgcn_logf(s);
}

__device__ __forceinline__ void async_copy16(const void* g, void* l) {
    __builtin_amdgcn_global_load_lds(
        (const __attribute__((address_space(1))) unsigned int*)g,
        (__attribute__((address_space(3))) unsigned int*)l, 16, 0, 0);
}

// ---- front: fproj GEMM + Wo->fp8 shuffle + cemb gather
// blk [0,256):   fproj tile (direct Wf transpose staging, bf16 MFMA)
// blk [256,328): Wo_s[k32][kg][n] = fp8(Wo[k32*32+kg*8+e][n] * 64), 8B entries
// blk [328,425): cemb[b][u][:] = bf16(E[ctx(b,u)][:])
__global__ __launch_bounds__(256, 2) void k_front(
    const float* __restrict__ frames, const float* __restrict__ Wf,
    const float* __restrict__ Wo, const float* __restrict__ E,
    const int* __restrict__ labels, bf16* __restrict__ fproj,
    long* __restrict__ Wo_s, bf16* __restrict__ cemb) {
    __shared__ bf16 Alds[64 * 40];
    __shared__ bf16 Blds[64 * 40];
    const int blk = blockIdx.x;
    const int tid = threadIdx.x;

    if (blk < 256) {
        const int r0 = (blk & 31) * 64;
        const int n0 = (blk >> 5) * 64;
        const int lane = tid & 63, w = tid >> 6;
        const int c = lane & 15, g = lane >> 4;

        const int srow = tid >> 2, sko = (tid & 3) * 8;
        const float* fptr = frames + (size_t)(r0 + srow) * FF + sko;
        const int q = tid >> 6, c64 = tid & 63;  // B-transpose staging coords

        f32x4 acc[4];
#pragma unroll
        for (int j = 0; j < 4; ++j) acc[j] = (f32x4){0.f, 0.f, 0.f, 0.f};

        for (int kt = 0; kt < FF; kt += 32) {
            float4 f1 = *(const float4*)(fptr + kt);
            float4 f2 = *(const float4*)(fptr + kt + 4);
            bf16x8 av = {(bf16)f1.x, (bf16)f1.y, (bf16)f1.z, (bf16)f1.w,
                         (bf16)f2.x, (bf16)f2.y, (bf16)f2.z, (bf16)f2.w};
            *(bf16x8*)&Alds[srow * 40 + sko] = av;
#pragma unroll
            for (int p = 0; p < 8; ++p) {
                float v = Wf[(size_t)(kt + q * 8 + p) * HH + n0 + c64];
                Blds[c64 * 40 + q * 8 + p] = (bf16)v;
            }
            __syncthreads();
            const int m = w * 16;
            bf16x8 af = *(const bf16x8*)&Alds[(m + c) * 40 + g * 8];
#pragma unroll
            for (int j = 0; j < 4; ++j) {
                bf16x8 bv = *(const bf16x8*)&Blds[(j * 16 + c) * 40 + g * 8];
                acc[j] = __builtin_amdgcn_mfma_f32_16x16x32_bf16(af, bv, acc[j], 0, 0, 0);
            }
            __syncthreads();
        }
        const int m = w * 16;
#pragma unroll
        for (int j = 0; j < 4; ++j)
#pragma unroll
            for (int r = 0; r < 4; ++r)
                fproj[(size_t)(r0 + m + g * 4 + r) * HH + n0 + j * 16 + c] = (bf16)acc[j][r];
    } else if (blk < 328) {
        int idx = (blk - 256) * 256 + tid;  // 0..18431
        int n = idx % NP;
        int rest = idx / NP;
        int kg = rest & 3;
        int k32 = rest >> 2;
        float v[8];
#pragma unroll
        for (int e = 0; e < 8; ++e) {
            int k = k32 * 32 + kg * 8 + e;
            v[e] = (n < NV) ? Wo[k * NV + n] * WOSCL : 0.f;
        }
        Wo_s[idx] = pack_fp8x8(v);
    } else {
        int u = blk - 328;  // 0..96
        for (int b = 0; b < BB; ++b) {
            int ctx = (u == 0) ? 0 : labels[b * UU + (u - 1)];
            const float* src = E + (size_t)ctx * HH;
            bf16* dst = cemb + ((size_t)b * NU + u) * HH;
            for (int i = tid; i < HH; i += 256) dst[i] = (bf16)src[i];
        }
    }
}

// ---- joint: logits = tanh(fproj[t]+cemb[u]) @ Wo  [fp8 MFMA path]
// grid (388, B), block 512 = 8 waves (4 M-slots x 2 N-halves), wave tile 32x144.
// A/B fragments are 8 fp8 per lane (one long); LDS traffic halved vs bf16.
__global__ __launch_bounds__(512, 4) void k_joint(
    const bf16* __restrict__ fproj, const bf16* __restrict__ cemb,
    const long* __restrict__ Wo_s, const int* __restrict__ labels,
    const int* __restrict__ num_frames, float* __restrict__ cl_arr) {
    __shared__ long A_s8[2][520];    // 2 x 4160 B; kg-plane stride 130 longs (bank rot)
    __shared__ long B_s8[2][1152];   // 2 x 9216 B; flat [kg][n] longs
    __shared__ float red[6 * 128];   // cross-wave LSE combine

    const int tid = threadIdx.x;
    const int b = blockIdx.y;
    const int r0 = blockIdx.x * 128;
    const int nf = num_frames[b];
    if (r0 / NU >= nf) return;  // whole tile beyond active frames: outputs unused

    const int lane = tid & 63, w = tid >> 6;
    const int wm = w & 3, wn = w >> 2;
    const int c = lane & 15, g = lane >> 4;

    // A-staging: 128 rows x 4 kg = 512 tasks, one per thread.
    const int arow = tid >> 2, akg = tid & 3;
    const int gr = r0 + arow;
    const int at = gr / NU, au = gr - at * NU;
    const bf16* pf = fproj + ((size_t)(b * TT + at)) * HH + akg * 8;
    const bf16* pc = cemb + ((size_t)(b * NU + au)) * HH + akg * 8;
    const int sdst8 = akg * 130 + arow;
    const char* wsrcB = (const char*)Wo_s + lane * 16;

    f32x4 acc[2][9];
#pragma unroll
    for (int mt = 0; mt < 2; ++mt)
#pragma unroll
        for (int j = 0; j < 9; ++j) acc[mt][j] = (f32x4){0.f, 0.f, 0.f, 0.f};

    const int aBase8 = g * 130 + (wm * 32 + c);
    const int bBase8 = g * 288 + (wn * 144 + c);

    // ---- prologue: stage k32=0 into buffer 0 ----
    {
        for (int ch = w; ch < 9; ch += 8)
            async_copy16(wsrcB + ch * 1024, (char*)&B_s8[0][0] + ch * 1024 + lane * 16);
        bf16x8 fv = *(const bf16x8*)pf;
        bf16x8 cv = *(const bf16x8*)pc;
        float tv[8];
#pragma unroll
        for (int e = 0; e < 8; ++e)
            tv[e] = fast_tanh((float)fv[e] + (float)cv[e]);
        A_s8[0][sdst8] = pack_fp8x8(tv);
        __syncthreads();
    }

    // ---- main loop: one barrier per k32 ----
    for (int i = 0; i < 16; ++i) {
        const int cur = i & 1, nxt = cur ^ 1;
        long af0 = A_s8[cur][aBase8];
        long af1 = A_s8[cur][aBase8 + 16];
#pragma unroll
        for (int j = 0; j < 9; ++j) {
            long bv = B_s8[cur][bBase8 + j * 16];
            acc[0][j] = __builtin_amdgcn_mfma_f32_16x16x32_fp8_fp8(af0, bv, acc[0][j], 0, 0, 0);
            acc[1][j] = __builtin_amdgcn_mfma_f32_16x16x32_fp8_fp8(af1, bv, acc[1][j], 0, 0, 0);
        }
        if (i < 15) {
            const int kt = (i + 1) * 32;
            bf16x8 fv2 = *(const bf16x8*)(pf + kt);
            bf16x8 cv2 = *(const bf16x8*)(pc + kt);
            const char* wk = wsrcB + (size_t)(i + 1) * 9216;
            for (int ch = w; ch < 9; ch += 8)
                async_copy16(wk + ch * 1024, (char*)&B_s8[nxt][0] + ch * 1024 + lane * 16);
            float tv[8];
#pragma unroll
            for (int e = 0; e < 8; ++e)
                tv[e] = fast_tanh((float)fv2[e] + (float)cv2[e]);
            A_s8[nxt][sdst8] = pack_fp8x8(tv);
        }
        __syncthreads();
    }

    // undo the Wo x64 pre-scale before LSE
#pragma unroll
    for (int mt = 0; mt < 2; ++mt)
#pragma unroll
        for (int j = 0; j < 9; ++j) acc[mt][j] = acc[mt][j] * INVWOSCL;

    // epilogue: per-wave partial lse over owned 144 cols, cross-wave combine in LDS
    float* pmax0 = red;
    float* pmax1 = red + 128;
    float* psum0 = red + 256;
    float* psum1 = red + 384;
    float* pblank = red + 512;
    float* plex = red + 640;

#pragma unroll
    for (int mt = 0; mt < 2; ++mt) {
#pragma unroll
        for (int r = 0; r < 4; ++r) {
            int row_in = wm * 32 + mt * 16 + g * 4 + r;
            int grr = r0 + row_in;
            int u = grr - (grr / NU) * NU;

            float mx = NEG_INF;
#pragma unroll
            for (int j = 0; j < 9; ++j) {
                int col = wn * 144 + j * 16 + c;
                if (col < NV) mx = fmaxf(mx, acc[mt][j][r]);
            }
#pragma unroll
            for (int s = 1; s < 16; s <<= 1) mx = fmaxf(mx, __shfl_xor(mx, s));
            float sum = 0.f;
#pragma unroll
            for (int j = 0; j < 9; ++j) {
                int col = wn * 144 + j * 16 + c;
                if (col < NV) sum += __expf(acc[mt][j][r] - mx);
            }
#pragma unroll
            for (int s = 1; s < 16; s <<= 1) sum += __shfl_xor(sum, s);

            int L = (u < UU) ? labels[b * UU + u] : -1;  // 1..256 or -1
            int lc = L - wn * 144;
            bool own = (lc >= 0) && (lc < 144);
            int src = (lane & 48) | (lc & 15);
            int jl = lc >> 4;
            float lexv = 0.f;
#pragma unroll
            for (int j = 0; j < 9; ++j) {
                float cand = __shfl(acc[mt][j][r], src);
                if (j == jl) lexv = cand;
            }
            float blankv = __shfl(acc[mt][0][r], lane & 48);  // col 0 (valid for wn==0)

            if (c == 0) {
                if (wn == 0) {
                    pmax0[row_in] = mx;
                    psum0[row_in] = sum;
                    pblank[row_in] = blankv;
                } else {
                    pmax1[row_in] = mx;
                    psum1[row_in] = sum;
                }
                if (own) plex[row_in] = lexv;
            }
        }
    }
    __syncthreads();
    if (tid < 128) {
        int grr = r0 + tid;
        int t = grr / NU, u = grr - t * NU;
        float m0 = pmax0[tid], m1 = pmax1[tid];
        float mx = fmaxf(m0, m1);
        float s = psum0[tid] * __expf(m0 - mx) + psum1[tid] * __expf(m1 - mx);
        float lse = mx + __logf(s);
        float2 v;
        v.x = pblank[tid] - lse;
        v.y = (u < UU) ? (plex[tid] - lse) : 0.f;
        *(float2*)&cl_arr[(((size_t)b * TT + t) * NU + u) * 2] = v;
    }
}

// ---- parallel depth-4 compaction: grid (NG, BB), block 128 (one thread per u).
__global__ __launch_bounds__(128) void k_compact(
    const float* __restrict__ cl, const int* __restrict__ num_frames,
    float* __restrict__ Dg) {
    const int g = blockIdx.x;
    const int b = blockIdx.y;
    const int u = threadIdx.x;
    if (u >= NU) return;
    const int nf = num_frames[b];
    const float2* P = (const float2*)(cl + (size_t)b * TT * NU * 2);

    auto fetch = [&](int t, int uu, float& bb, float& ll) {
        if (uu <= UU) {
            float2 z = P[t * NU + uu];
            bool act = t < nf;
            bb = act ? z.x * LOG2E : 0.f;
            ll = (act && uu < UU) ? z.y * LOG2E : NEG_INF;
        } else {
            bb = NEG_INF;
            ll = NEG_INF;
        }
    };

    const int t0 = g * 4;
    float b0, l0, b1u, l1u, b1u1, l1u1;
    fetch(t0, u, b0, l0);
    fetch(t0 + 1, u, b1u, l1u);
    fetch(t0 + 1, u + 1, b1u1, l1u1);
    float A0 = b0 + b1u;
    float A1 = lae2(l0 + b1u1, b0 + l1u);
    float A2 = l0 + l1u1;
    float B0[3], B1[3], B2[3];
#pragma unroll
    for (int j = 0; j < 3; ++j) {
        float b2v, l2v, b3v, l3v, b3n, l3n;
        fetch(t0 + 2, u + j, b2v, l2v);
        fetch(t0 + 3, u + j, b3v, l3v);
        fetch(t0 + 3, u + j + 1, b3n, l3n);
        B0[j] = b2v + b3v;
        B1[j] = lae2(l2v + b3n, b2v + l3v);
        B2[j] = l2v + l3n;
    }
    float* d = Dg + ((size_t)b * NG + g) * GSTRIDE;
    d[u] = A0 + B0[0];
    d[104 + u] = lae2(A1 + B0[1], A0 + B1[0]);
    d[208 + u] = lse3_2(A2 + B0[2], A1 + B1[1], A0 + B2[0]);
    d[312 + u] = lae2(A2 + B1[2], A1 + B2[1]);
    d[416 + u] = A2 + B2[2];
}

// ---- serial chain: 1 wave per batch, 128 banded-lse5 steps, 8-deep reg ring.
__global__ __launch_bounds__(64) void k_dpser(
    const float* __restrict__ Dg, const int* __restrict__ num_labels,
    float* __restrict__ out) {
    const int b = blockIdx.x;
    const int lane = threadIdx.x;
    const float* D = Dg + (size_t)b * NG * GSTRIDE;
    const int lo_u = lane;
    const int hi_u = 64 + ((lane < 33) ? lane : 0);

    float a_lo = (lane == 0) ? 0.f : NEG_INF;  // alpha[u=lane] (base-2)
    float a_hi = NEG_INF;                      // alpha[u=64+lane], lane<33

    constexpr int R = 8;
    float blo[R][5], bhi[R][5];
#pragma unroll
    for (int g = 0; g < R; ++g)
#pragma unroll
        for (int k = 0; k < 5; ++k) {
            blo[g][k] = D[g * GSTRIDE + k * 104 + lo_u];
            bhi[g][k] = D[g * GSTRIDE + k * 104 + hi_u];
        }

#pragma unroll 8
    for (int g = 0; g < NG; ++g) {
        const int slot = g & (R - 1);
        float el[5], eh[5];
#pragma unroll
        for (int k = 0; k < 5; ++k) {
            el[k] = a_lo + blo[slot][k];
            eh[k] = a_hi + bhi[slot][k];
        }
        const int gp = g + R;
        if (gp < NG) {
#pragma unroll
            for (int k = 0; k < 5; ++k) {
                blo[slot][k] = D[gp * GSTRIDE + k * 104 + lo_u];
                bhi[slot][k] = D[gp * GSTRIDE + k * 104 + hi_u];
            }
        }
        float ml[5], mh[5];
        ml[0] = el[0];
        mh[0] = eh[0];
#pragma unroll
        for (int k = 1; k < 5; ++k) {
            float su = __shfl_up(el[k], k);
            ml[k] = (lane >= k) ? su : NEG_INF;
            float sh = __shfl_up(eh[k], k);
            float xl = __shfl(el[k], 64 - k + lane);  // lo lanes 63..64-k
            mh[k] = (lane >= k) ? sh : xl;
        }
        a_lo = lse5_2(ml[0], ml[1], ml[2], ml[3], ml[4]);
        float nh = lse5_2(mh[0], mh[1], mh[2], mh[3], mh[4]);
        if (lane < 33) a_hi = nh;
    }

    const int nl = num_labels[b];
    float res = (nl < 64) ? __shfl(a_lo, nl) : __shfl(a_hi, nl - 64);
    if (lane == 0) out[b] = -res * LN2;  // back to natural-log domain
}

extern "C" void kernel_launch(void* const* d_in, const int* in_sizes, int n_in,
                              void* d_out, int out_size, void* d_ws, size_t ws_size,
                              hipStream_t stream) {
    const float* frames = (const float*)d_in[0];
    const int* num_frames = (const int*)d_in[1];
    const int* labels = (const int*)d_in[2];
    const int* num_labels = (const int*)d_in[3];
    const float* Wf = (const float*)d_in[4];
    const float* E = (const float*)d_in[5];
    const float* Wo = (const float*)d_in[6];
    float* out = (float*)d_out;

    char* ws = (char*)d_ws;
    size_t off = 0;
    long* Wo_s = (long*)(ws + off); off += (size_t)18432 * 8;                 // 144 KiB
    bf16* cemb = (bf16*)(ws + off); off += (size_t)BB * NU * HH * 2;          // 388 KiB
    off = (off + 255) & ~(size_t)255;
    bf16* fproj = (bf16*)(ws + off); off += (size_t)BB * TT * HH * 2;         // 2 MiB
    off = (off + 255) & ~(size_t)255;
    float* cl_arr = (float*)(ws + off); off += (size_t)BB * TT * NU * 2 * 4;  // 1.52 MiB
    off = (off + 255) & ~(size_t)255;
    float* Dg = (float*)(ws + off); off += (size_t)BB * NG * GSTRIDE * 4;     // 1.02 MiB

    hipLaunchKernelGGL(k_front, dim3(425), dim3(256), 0, stream,
                       frames, Wf, Wo, E, labels, fproj, Wo_s, cemb);
    hipLaunchKernelGGL(k_joint, dim3((TT * NU) / 128, BB), dim3(512), 0, stream,
                       fproj, cemb, Wo_s, labels, num_frames, cl_arr);
    hipLaunchKernelGGL(k_compact, dim3(NG, BB), dim3(128), 0, stream,
                       cl_arr, num_frames, Dg);
    hipLaunchKernelGGL(k_dpser, dim3(BB), dim3(64), 0, stream,
                       Dg, num_labels, out);
}

// Round 15
// 202.190 us; speedup vs baseline: 1.1198x; 1.0142x over previous
//
#include <hip/hip_runtime.h>
#include <hip/hip_bf16.h>

// RecognitionLattice: RNN-T style lattice loss.
// k_front: fproj GEMM (direct fp32-Wf transpose staging, f16 out) + Wo->fp8
//          shuffle + cemb gather (f16) as block ranges of ONE launch
// -> k_joint: h=tanh(fproj+cemb) in PACKED f16 (v_pk_*) -> fp8 @ Wo_fp8
//    (mfma 16x16x32_fp8_fp8), dbuf single-barrier K-loop, fused LSE
// -> k_compact: parallel depth-4 semiring compaction -> Dg
// -> k_dpser: 1 wave/batch serial chain, 128 banded-lse5 steps, 8-deep reg ring.

#define BB 4
#define TT 512
#define UU 96
#define FF 512
#define HH 512
#define VV 256
#define NV (VV + 1)    // 257 vocab incl. blank
#define NU (UU + 1)    // 97 lattice rows per t
#define NP 288         // 18*16 padded N
#define NEG_INF (-1e30f)
#define LOG2E 1.4426950408889634f
#define LN2 0.6931471805599453f
#define NG 128         // groups of 4 t-steps
#define GSTRIDE 520    // 5*104 floats per group operator
#define WOSCL 64.0f    // Wo pre-scale into fp8 normal range
#define INVWOSCL 0.015625f

typedef _Float16 f16;
typedef __attribute__((ext_vector_type(8))) _Float16 f16x8;
typedef __bf16 bf16;
typedef __bf16 bf16x8 __attribute__((ext_vector_type(8)));
typedef float f32x4 __attribute__((ext_vector_type(4)));

__device__ __forceinline__ f16x8 splat8(float s) {
    f16 v = (f16)s;
    f16x8 r = {v, v, v, v, v, v, v, v};
    return r;
}

// tanh via clamped odd polynomial in PACKED f16 (v_pk_* dual-issue), then
// fp8 e4m3 pack. Max poly err ~0.007 on [-2,2]; f16 intermediate err ~1e-3
// << fp8 output quantization. No __half2 (header overload clash) — raw
// _Float16 vectors lower to v_pk_add/mul/min/max_f16.
__device__ __forceinline__ long tanh_pack8(f16x8 fv8, f16x8 cv8) {
    f16x8 x = fv8 + cv8;
    x = __builtin_elementwise_min(__builtin_elementwise_max(x, splat8(-2.0f)),
                                  splat8(2.0f));
    f16x8 y = x * x;
    f16x8 q = y * splat8(-0.0067528f) + splat8(0.0700672f);
    q = y * q + splat8(-0.301720f);
    q = y * q + splat8(1.0f);
    f16x8 t = x * q;
    int lo = 0, hi = 0;
    lo = __builtin_amdgcn_cvt_pk_fp8_f32((float)t[0], (float)t[1], lo, false);
    lo = __builtin_amdgcn_cvt_pk_fp8_f32((float)t[2], (float)t[3], lo, true);
    hi = __builtin_amdgcn_cvt_pk_fp8_f32((float)t[4], (float)t[5], hi, false);
    hi = __builtin_amdgcn_cvt_pk_fp8_f32((float)t[6], (float)t[7], hi, true);
    return (long)(((unsigned long long)(unsigned int)lo) |
                  (((unsigned long long)(unsigned int)hi) << 32));
}

// pack 8 floats -> 8 fp8 e4m3 (for Wo prep)
__device__ __forceinline__ long pack_fp8x8(const float* v) {
    int lo = 0, hi = 0;
    lo = __builtin_amdgcn_cvt_pk_fp8_f32(v[0], v[1], lo, false);
    lo = __builtin_amdgcn_cvt_pk_fp8_f32(v[2], v[3], lo, true);
    hi = __builtin_amdgcn_cvt_pk_fp8_f32(v[4], v[5], hi, false);
    hi = __builtin_amdgcn_cvt_pk_fp8_f32(v[6], v[7], hi, true);
    return (long)(((unsigned long long)(unsigned int)lo) |
                  (((unsigned long long)(unsigned int)hi) << 32));
}

// base-2 log-domain ops (inputs/outputs already scaled by log2(e))
__device__ __forceinline__ float lae2(float x, float y) {
    float m = fmaxf(x, y);
    float d = fminf(x, y) - m;
    return m + __builtin_amdgcn_logf(1.0f + __builtin_amdgcn_exp2f(d));
}

__device__ __forceinline__ float lse3_2(float x, float y, float z) {
    float m = fmaxf(fmaxf(x, y), z);
    float s = __builtin_amdgcn_exp2f(x - m) + __builtin_amdgcn_exp2f(y - m) +
              __builtin_amdgcn_exp2f(z - m);
    return m + __builtin_amdgcn_logf(s);
}

__device__ __forceinline__ float lse5_2(float a, float b, float c, float d, float e) {
    float m = fmaxf(fmaxf(fmaxf(a, b), fmaxf(c, d)), e);
    float s = __builtin_amdgcn_exp2f(a - m) + __builtin_amdgcn_exp2f(b - m) +
              __builtin_amdgcn_exp2f(c - m) + __builtin_amdgcn_exp2f(d - m) +
              __builtin_amdgcn_exp2f(e - m);
    return m + __builtin_amdgcn_logf(s);
}

__device__ __forceinline__ void async_copy16(const void* g, void* l) {
    __builtin_amdgcn_global_load_lds(
        (const __attribute__((address_space(1))) unsigned int*)g,
        (__attribute__((address_space(3))) unsigned int*)l, 16, 0, 0);
}

// ---- front: fproj GEMM + Wo->fp8 shuffle + cemb gather
// blk [0,256):   fproj tile (direct Wf transpose staging, bf16 MFMA, f16 out)
// blk [256,328): Wo_s[k32][kg][n] = fp8(Wo[k32*32+kg*8+e][n] * 64), 8B entries
// blk [328,425): cemb[b][u][:] = f16(E[ctx(b,u)][:])
__global__ __launch_bounds__(256, 2) void k_front(
    const float* __restrict__ frames, const float* __restrict__ Wf,
    const float* __restrict__ Wo, const float* __restrict__ E,
    const int* __restrict__ labels, f16* __restrict__ fproj,
    long* __restrict__ Wo_s, f16* __restrict__ cemb) {
    __shared__ bf16 Alds[64 * 40];
    __shared__ bf16 Blds[64 * 40];
    const int blk = blockIdx.x;
    const int tid = threadIdx.x;

    if (blk < 256) {
        const int r0 = (blk & 31) * 64;
        const int n0 = (blk >> 5) * 64;
        const int lane = tid & 63, w = tid >> 6;
        const int c = lane & 15, g = lane >> 4;

        const int srow = tid >> 2, sko = (tid & 3) * 8;
        const float* fptr = frames + (size_t)(r0 + srow) * FF + sko;
        const int q = tid >> 6, c64 = tid & 63;  // B-transpose staging coords

        f32x4 acc[4];
#pragma unroll
        for (int j = 0; j < 4; ++j) acc[j] = (f32x4){0.f, 0.f, 0.f, 0.f};

        for (int kt = 0; kt < FF; kt += 32) {
            float4 f1 = *(const float4*)(fptr + kt);
            float4 f2 = *(const float4*)(fptr + kt + 4);
            bf16x8 av = {(bf16)f1.x, (bf16)f1.y, (bf16)f1.z, (bf16)f1.w,
                         (bf16)f2.x, (bf16)f2.y, (bf16)f2.z, (bf16)f2.w};
            *(bf16x8*)&Alds[srow * 40 + sko] = av;
#pragma unroll
            for (int p = 0; p < 8; ++p) {
                float v = Wf[(size_t)(kt + q * 8 + p) * HH + n0 + c64];
                Blds[c64 * 40 + q * 8 + p] = (bf16)v;
            }
            __syncthreads();
            const int m = w * 16;
            bf16x8 af = *(const bf16x8*)&Alds[(m + c) * 40 + g * 8];
#pragma unroll
            for (int j = 0; j < 4; ++j) {
                bf16x8 bv = *(const bf16x8*)&Blds[(j * 16 + c) * 40 + g * 8];
                acc[j] = __builtin_amdgcn_mfma_f32_16x16x32_bf16(af, bv, acc[j], 0, 0, 0);
            }
            __syncthreads();
        }
        const int m = w * 16;
#pragma unroll
        for (int j = 0; j < 4; ++j)
#pragma unroll
            for (int r = 0; r < 4; ++r)
                fproj[(size_t)(r0 + m + g * 4 + r) * HH + n0 + j * 16 + c] = (f16)acc[j][r];
    } else if (blk < 328) {
        int idx = (blk - 256) * 256 + tid;  // 0..18431
        int n = idx % NP;
        int rest = idx / NP;
        int kg = rest & 3;
        int k32 = rest >> 2;
        float v[8];
#pragma unroll
        for (int e = 0; e < 8; ++e) {
            int k = k32 * 32 + kg * 8 + e;
            v[e] = (n < NV) ? Wo[k * NV + n] * WOSCL : 0.f;
        }
        Wo_s[idx] = pack_fp8x8(v);
    } else {
        int u = blk - 328;  // 0..96
        for (int b = 0; b < BB; ++b) {
            int ctx = (u == 0) ? 0 : labels[b * UU + (u - 1)];
            const float* src = E + (size_t)ctx * HH;
            f16* dst = cemb + ((size_t)b * NU + u) * HH;
            for (int i = tid; i < HH; i += 256) dst[i] = (f16)src[i];
        }
    }
}

// ---- joint: logits = tanh(fproj[t]+cemb[u]) @ Wo  [fp8 MFMA, packed-f16 staging]
// grid (388, B), block 512 = 8 waves (4 M-slots x 2 N-halves), wave tile 32x144.
__global__ __launch_bounds__(512, 4) void k_joint(
    const f16* __restrict__ fproj, const f16* __restrict__ cemb,
    const long* __restrict__ Wo_s, const int* __restrict__ labels,
    const int* __restrict__ num_frames, float* __restrict__ cl_arr) {
    __shared__ long A_s8[2][520];    // 2 x 4160 B; kg-plane stride 130 longs (bank rot)
    __shared__ long B_s8[2][1152];   // 2 x 9216 B; flat [kg][n] longs
    __shared__ float red[6 * 128];   // cross-wave LSE combine

    const int tid = threadIdx.x;
    const int b = blockIdx.y;
    const int r0 = blockIdx.x * 128;
    const int nf = num_frames[b];
    if (r0 / NU >= nf) return;  // whole tile beyond active frames: outputs unused

    const int lane = tid & 63, w = tid >> 6;
    const int wm = w & 3, wn = w >> 2;
    const int c = lane & 15, g = lane >> 4;

    // A-staging: 128 rows x 4 kg = 512 tasks, one per thread.
    const int arow = tid >> 2, akg = tid & 3;
    const int gr = r0 + arow;
    const int at = gr / NU, au = gr - at * NU;
    const f16* pf = fproj + ((size_t)(b * TT + at)) * HH + akg * 8;
    const f16* pc = cemb + ((size_t)(b * NU + au)) * HH + akg * 8;
    const int sdst8 = akg * 130 + arow;
    const char* wsrcB = (const char*)Wo_s + lane * 16;

    f32x4 acc[2][9];
#pragma unroll
    for (int mt = 0; mt < 2; ++mt)
#pragma unroll
        for (int j = 0; j < 9; ++j) acc[mt][j] = (f32x4){0.f, 0.f, 0.f, 0.f};

    const int aBase8 = g * 130 + (wm * 32 + c);
    const int bBase8 = g * 288 + (wn * 144 + c);

    // ---- prologue: stage k32=0 into buffer 0 ----
    {
        for (int ch = w; ch < 9; ch += 8)
            async_copy16(wsrcB + ch * 1024, (char*)&B_s8[0][0] + ch * 1024 + lane * 16);
        f16x8 fv = *(const f16x8*)pf;
        f16x8 cv = *(const f16x8*)pc;
        A_s8[0][sdst8] = tanh_pack8(fv, cv);
        __syncthreads();
    }

    // ---- main loop: one barrier per k32 ----
    for (int i = 0; i < 16; ++i) {
        const int cur = i & 1, nxt = cur ^ 1;
        long af0 = A_s8[cur][aBase8];
        long af1 = A_s8[cur][aBase8 + 16];
#pragma unroll
        for (int j = 0; j < 9; ++j) {
            long bv = B_s8[cur][bBase8 + j * 16];
            acc[0][j] = __builtin_amdgcn_mfma_f32_16x16x32_fp8_fp8(af0, bv, acc[0][j], 0, 0, 0);
            acc[1][j] = __builtin_amdgcn_mfma_f32_16x16x32_fp8_fp8(af1, bv, acc[1][j], 0, 0, 0);
        }
        if (i < 15) {
            const int kt = (i + 1) * 32;
            f16x8 fv2 = *(const f16x8*)(pf + kt);
            f16x8 cv2 = *(const f16x8*)(pc + kt);
            const char* wk = wsrcB + (size_t)(i + 1) * 9216;
            for (int ch = w; ch < 9; ch += 8)
                async_copy16(wk + ch * 1024, (char*)&B_s8[nxt][0] + ch * 1024 + lane * 16);
            A_s8[nxt][sdst8] = tanh_pack8(fv2, cv2);
        }
        __syncthreads();
    }

    // undo the Wo x64 pre-scale before LSE
#pragma unroll
    for (int mt = 0; mt < 2; ++mt)
#pragma unroll
        for (int j = 0; j < 9; ++j) acc[mt][j] = acc[mt][j] * INVWOSCL;

    // epilogue: per-wave partial lse over owned 144 cols, cross-wave combine in LDS
    float* pmax0 = red;
    float* pmax1 = red + 128;
    float* psum0 = red + 256;
    float* psum1 = red + 384;
    float* pblank = red + 512;
    float* plex = red + 640;

#pragma unroll
    for (int mt = 0; mt < 2; ++mt) {
#pragma unroll
        for (int r = 0; r < 4; ++r) {
            int row_in = wm * 32 + mt * 16 + g * 4 + r;
            int grr = r0 + row_in;
            int u = grr - (grr / NU) * NU;

            float mx = NEG_INF;
#pragma unroll
            for (int j = 0; j < 9; ++j) {
                int col = wn * 144 + j * 16 + c;
                if (col < NV) mx = fmaxf(mx, acc[mt][j][r]);
            }
#pragma unroll
            for (int s = 1; s < 16; s <<= 1) mx = fmaxf(mx, __shfl_xor(mx, s));
            float sum = 0.f;
#pragma unroll
            for (int j = 0; j < 9; ++j) {
                int col = wn * 144 + j * 16 + c;
                if (col < NV) sum += __expf(acc[mt][j][r] - mx);
            }
#pragma unroll
            for (int s = 1; s < 16; s <<= 1) sum += __shfl_xor(sum, s);

            int L = (u < UU) ? labels[b * UU + u] : -1;  // 1..256 or -1
            int lc = L - wn * 144;
            bool own = (lc >= 0) && (lc < 144);
            int src = (lane & 48) | (lc & 15);
            int jl = lc >> 4;
            float lexv = 0.f;
#pragma unroll
            for (int j = 0; j < 9; ++j) {
                float cand = __shfl(acc[mt][j][r], src);
                if (j == jl) lexv = cand;
            }
            float blankv = __shfl(acc[mt][0][r], lane & 48);  // col 0 (valid for wn==0)

            if (c == 0) {
                if (wn == 0) {
                    pmax0[row_in] = mx;
                    psum0[row_in] = sum;
                    pblank[row_in] = blankv;
                } else {
                    pmax1[row_in] = mx;
                    psum1[row_in] = sum;
                }
                if (own) plex[row_in] = lexv;
            }
        }
    }
    __syncthreads();
    if (tid < 128) {
        int grr = r0 + tid;
        int t = grr / NU, u = grr - t * NU;
        float m0 = pmax0[tid], m1 = pmax1[tid];
        float mx = fmaxf(m0, m1);
        float s = psum0[tid] * __expf(m0 - mx) + psum1[tid] * __expf(m1 - mx);
        float lse = mx + __logf(s);
        float2 v;
        v.x = pblank[tid] - lse;
        v.y = (u < UU) ? (plex[tid] - lse) : 0.f;
        *(float2*)&cl_arr[(((size_t)b * TT + t) * NU + u) * 2] = v;
    }
}

// ---- parallel depth-4 compaction: grid (NG, BB), block 128 (one thread per u).
__global__ __launch_bounds__(128) void k_compact(
    const float* __restrict__ cl, const int* __restrict__ num_frames,
    float* __restrict__ Dg) {
    const int g = blockIdx.x;
    const int b = blockIdx.y;
    const int u = threadIdx.x;
    if (u >= NU) return;
    const int nf = num_frames[b];
    const float2* P = (const float2*)(cl + (size_t)b * TT * NU * 2);

    auto fetch = [&](int t, int uu, float& bb, float& ll) {
        if (uu <= UU) {
            float2 z = P[t * NU + uu];
            bool act = t < nf;
            bb = act ? z.x * LOG2E : 0.f;
            ll = (act && uu < UU) ? z.y * LOG2E : NEG_INF;
        } else {
            bb = NEG_INF;
            ll = NEG_INF;
        }
    };

    const int t0 = g * 4;
    float b0, l0, b1u, l1u, b1u1, l1u1;
    fetch(t0, u, b0, l0);
    fetch(t0 + 1, u, b1u, l1u);
    fetch(t0 + 1, u + 1, b1u1, l1u1);
    float A0 = b0 + b1u;
    float A1 = lae2(l0 + b1u1, b0 + l1u);
    float A2 = l0 + l1u1;
    float B0[3], B1[3], B2[3];
#pragma unroll
    for (int j = 0; j < 3; ++j) {
        float b2v, l2v, b3v, l3v, b3n, l3n;
        fetch(t0 + 2, u + j, b2v, l2v);
        fetch(t0 + 3, u + j, b3v, l3v);
        fetch(t0 + 3, u + j + 1, b3n, l3n);
        B0[j] = b2v + b3v;
        B1[j] = lae2(l2v + b3n, b2v + l3v);
        B2[j] = l2v + l3n;
    }
    float* d = Dg + ((size_t)b * NG + g) * GSTRIDE;
    d[u] = A0 + B0[0];
    d[104 + u] = lae2(A1 + B0[1], A0 + B1[0]);
    d[208 + u] = lse3_2(A2 + B0[2], A1 + B1[1], A0 + B2[0]);
    d[312 + u] = lae2(A2 + B1[2], A1 + B2[1]);
    d[416 + u] = A2 + B2[2];
}

// ---- serial chain: 1 wave per batch, 128 banded-lse5 steps, 8-deep reg ring.
__global__ __launch_bounds__(64) void k_dpser(
    const float* __restrict__ Dg, const int* __restrict__ num_labels,
    float* __restrict__ out) {
    const int b = blockIdx.x;
    const int lane = threadIdx.x;
    const float* D = Dg + (size_t)b * NG * GSTRIDE;
    const int lo_u = lane;
    const int hi_u = 64 + ((lane < 33) ? lane : 0);

    float a_lo = (lane == 0) ? 0.f : NEG_INF;  // alpha[u=lane] (base-2)
    float a_hi = NEG_INF;                      // alpha[u=64+lane], lane<33

    constexpr int R = 8;
    float blo[R][5], bhi[R][5];
#pragma unroll
    for (int g = 0; g < R; ++g)
#pragma unroll
        for (int k = 0; k < 5; ++k) {
            blo[g][k] = D[g * GSTRIDE + k * 104 + lo_u];
            bhi[g][k] = D[g * GSTRIDE + k * 104 + hi_u];
        }

#pragma unroll 8
    for (int g = 0; g < NG; ++g) {
        const int slot = g & (R - 1);
        float el[5], eh[5];
#pragma unroll
        for (int k = 0; k < 5; ++k) {
            el[k] = a_lo + blo[slot][k];
            eh[k] = a_hi + bhi[slot][k];
        }
        const int gp = g + R;
        if (gp < NG) {
#pragma unroll
            for (int k = 0; k < 5; ++k) {
                blo[slot][k] = D[gp * GSTRIDE + k * 104 + lo_u];
                bhi[slot][k] = D[gp * GSTRIDE + k * 104 + hi_u];
            }
        }
        float ml[5], mh[5];
        ml[0] = el[0];
        mh[0] = eh[0];
#pragma unroll
        for (int k = 1; k < 5; ++k) {
            float su = __shfl_up(el[k], k);
            ml[k] = (lane >= k) ? su : NEG_INF;
            float sh = __shfl_up(eh[k], k);
            float xl = __shfl(el[k], 64 - k + lane);  // lo lanes 63..64-k
            mh[k] = (lane >= k) ? sh : xl;
        }
        a_lo = lse5_2(ml[0], ml[1], ml[2], ml[3], ml[4]);
        float nh = lse5_2(mh[0], mh[1], mh[2], mh[3], mh[4]);
        if (lane < 33) a_hi = nh;
    }

    const int nl = num_labels[b];
    float res = (nl < 64) ? __shfl(a_lo, nl) : __shfl(a_hi, nl - 64);
    if (lane == 0) out[b] = -res * LN2;  // back to natural-log domain
}

extern "C" void kernel_launch(void* const* d_in, const int* in_sizes, int n_in,
                              void* d_out, int out_size, void* d_ws, size_t ws_size,
                              hipStream_t stream) {
    const float* frames = (const float*)d_in[0];
    const int* num_frames = (const int*)d_in[1];
    const int* labels = (const int*)d_in[2];
    const int* num_labels = (const int*)d_in[3];
    const float* Wf = (const float*)d_in[4];
    const float* E = (const float*)d_in[5];
    const float* Wo = (const float*)d_in[6];
    float* out = (float*)d_out;

    char* ws = (char*)d_ws;
    size_t off = 0;
    long* Wo_s = (long*)(ws + off); off += (size_t)18432 * 8;                 // 144 KiB
    f16* cemb = (f16*)(ws + off); off += (size_t)BB * NU * HH * 2;            // 388 KiB
    off = (off + 255) & ~(size_t)255;
    f16* fproj = (f16*)(ws + off); off += (size_t)BB * TT * HH * 2;           // 2 MiB
    off = (off + 255) & ~(size_t)255;
    float* cl_arr = (float*)(ws + off); off += (size_t)BB * TT * NU * 2 * 4;  // 1.52 MiB
    off = (off + 255) & ~(size_t)255;
    float* Dg = (float*)(ws + off); off += (size_t)BB * NG * GSTRIDE * 4;     // 1.02 MiB

    hipLaunchKernelGGL(k_front, dim3(425), dim3(256), 0, stream,
                       frames, Wf, Wo, E, labels, fproj, Wo_s, cemb);
    hipLaunchKernelGGL(k_joint, dim3((TT * NU) / 128, BB), dim3(512), 0, stream,
                       fproj, cemb, Wo_s, labels, num_frames, cl_arr);
    hipLaunchKernelGGL(k_compact, dim3(NG, BB), dim3(128), 0, stream,
                       cl_arr, num_frames, Dg);
    hipLaunchKernelGGL(k_dpser, dim3(BB), dim3(64), 0, stream,
                       Dg, num_labels, out);
}

// Round 16
// 202.048 us; speedup vs baseline: 1.1206x; 1.0007x over previous
//
#include <hip/hip_runtime.h>
#include <hip/hip_bf16.h>

// RecognitionLattice: RNN-T style lattice loss.
// k_front: fproj GEMM (direct fp32-Wf transpose staging, f16 out) + Wo->fp8
//          shuffle + cemb gather (f16) as block ranges of ONE launch
// -> k_joint: h=tanh(fproj+cemb) packed-f16 -> fp8 @ Wo_fp8, BK=64 K-loop
//    (8 barriers), B-async issued pre-MFMA for max flight, fused LSE
// -> k_compact: parallel depth-4 semiring compaction -> Dg
// -> k_dpser: 1 wave/batch serial chain, 128 banded-lse5 steps, 8-deep reg ring.

#define BB 4
#define TT 512
#define UU 96
#define FF 512
#define HH 512
#define VV 256
#define NV (VV + 1)    // 257 vocab incl. blank
#define NU (UU + 1)    // 97 lattice rows per t
#define NP 288         // 18*16 padded N
#define NEG_INF (-1e30f)
#define LOG2E 1.4426950408889634f
#define LN2 0.6931471805599453f
#define NG 128         // groups of 4 t-steps
#define GSTRIDE 520    // 5*104 floats per group operator
#define WOSCL 64.0f    // Wo pre-scale into fp8 normal range
#define INVWOSCL 0.015625f

typedef _Float16 f16;
typedef __attribute__((ext_vector_type(8))) _Float16 f16x8;
typedef __bf16 bf16;
typedef __bf16 bf16x8 __attribute__((ext_vector_type(8)));
typedef float f32x4 __attribute__((ext_vector_type(4)));

__device__ __forceinline__ f16x8 splat8(float s) {
    f16 v = (f16)s;
    f16x8 r = {v, v, v, v, v, v, v, v};
    return r;
}

// tanh via clamped odd polynomial in PACKED f16 (v_pk_* dual-issue), then
// fp8 e4m3 pack. Max poly err ~0.007 on [-2,2]; f16 intermediate err ~1e-3
// << fp8 output quantization.
__device__ __forceinline__ long tanh_pack8(f16x8 fv8, f16x8 cv8) {
    f16x8 x = fv8 + cv8;
    x = __builtin_elementwise_min(__builtin_elementwise_max(x, splat8(-2.0f)),
                                  splat8(2.0f));
    f16x8 y = x * x;
    f16x8 q = y * splat8(-0.0067528f) + splat8(0.0700672f);
    q = y * q + splat8(-0.301720f);
    q = y * q + splat8(1.0f);
    f16x8 t = x * q;
    int lo = 0, hi = 0;
    lo = __builtin_amdgcn_cvt_pk_fp8_f32((float)t[0], (float)t[1], lo, false);
    lo = __builtin_amdgcn_cvt_pk_fp8_f32((float)t[2], (float)t[3], lo, true);
    hi = __builtin_amdgcn_cvt_pk_fp8_f32((float)t[4], (float)t[5], hi, false);
    hi = __builtin_amdgcn_cvt_pk_fp8_f32((float)t[6], (float)t[7], hi, true);
    return (long)(((unsigned long long)(unsigned int)lo) |
                  (((unsigned long long)(unsigned int)hi) << 32));
}

// pack 8 floats -> 8 fp8 e4m3 (for Wo prep)
__device__ __forceinline__ long pack_fp8x8(const float* v) {
    int lo = 0, hi = 0;
    lo = __builtin_amdgcn_cvt_pk_fp8_f32(v[0], v[1], lo, false);
    lo = __builtin_amdgcn_cvt_pk_fp8_f32(v[2], v[3], lo, true);
    hi = __builtin_amdgcn_cvt_pk_fp8_f32(v[4], v[5], hi, false);
    hi = __builtin_amdgcn_cvt_pk_fp8_f32(v[6], v[7], hi, true);
    return (long)(((unsigned long long)(unsigned int)lo) |
                  (((unsigned long long)(unsigned int)hi) << 32));
}

// base-2 log-domain ops (inputs/outputs already scaled by log2(e))
__device__ __forceinline__ float lae2(float x, float y) {
    float m = fmaxf(x, y);
    float d = fminf(x, y) - m;
    return m + __builtin_amdgcn_logf(1.0f + __builtin_amdgcn_exp2f(d));
}

__device__ __forceinline__ float lse3_2(float x, float y, float z) {
    float m = fmaxf(fmaxf(x, y), z);
    float s = __builtin_amdgcn_exp2f(x - m) + __builtin_amdgcn_exp2f(y - m) +
              __builtin_amdgcn_exp2f(z - m);
    return m + __builtin_amdgcn_logf(s);
}

__device__ __forceinline__ float lse5_2(float a, float b, float c, float d, float e) {
    float m = fmaxf(fmaxf(fmaxf(a, b), fmaxf(c, d)), e);
    float s = __builtin_amdgcn_exp2f(a - m) + __builtin_amdgcn_exp2f(b - m) +
              __builtin_amdgcn_exp2f(c - m) + __builtin_amdgcn_exp2f(d - m) +
              __builtin_amdgcn_exp2f(e - m);
    return m + __builtin_amdgcn_logf(s);
}

__device__ __forceinline__ void async_copy16(const void* g, void* l) {
    __builtin_amdgcn_global_load_lds(
        (const __attribute__((address_space(1))) unsigned int*)g,
        (__attribute__((address_space(3))) unsigned int*)l, 16, 0, 0);
}

// ---- front: fproj GEMM + Wo->fp8 shuffle + cemb gather
__global__ __launch_bounds__(256, 2) void k_front(
    const float* __restrict__ frames, const float* __restrict__ Wf,
    const float* __restrict__ Wo, const float* __restrict__ E,
    const int* __restrict__ labels, f16* __restrict__ fproj,
    long* __restrict__ Wo_s, f16* __restrict__ cemb) {
    __shared__ bf16 Alds[64 * 40];
    __shared__ bf16 Blds[64 * 40];
    const int blk = blockIdx.x;
    const int tid = threadIdx.x;

    if (blk < 256) {
        const int r0 = (blk & 31) * 64;
        const int n0 = (blk >> 5) * 64;
        const int lane = tid & 63, w = tid >> 6;
        const int c = lane & 15, g = lane >> 4;

        const int srow = tid >> 2, sko = (tid & 3) * 8;
        const float* fptr = frames + (size_t)(r0 + srow) * FF + sko;
        const int q = tid >> 6, c64 = tid & 63;  // B-transpose staging coords

        f32x4 acc[4];
#pragma unroll
        for (int j = 0; j < 4; ++j) acc[j] = (f32x4){0.f, 0.f, 0.f, 0.f};

        for (int kt = 0; kt < FF; kt += 32) {
            float4 f1 = *(const float4*)(fptr + kt);
            float4 f2 = *(const float4*)(fptr + kt + 4);
            bf16x8 av = {(bf16)f1.x, (bf16)f1.y, (bf16)f1.z, (bf16)f1.w,
                         (bf16)f2.x, (bf16)f2.y, (bf16)f2.z, (bf16)f2.w};
            *(bf16x8*)&Alds[srow * 40 + sko] = av;
#pragma unroll
            for (int p = 0; p < 8; ++p) {
                float v = Wf[(size_t)(kt + q * 8 + p) * HH + n0 + c64];
                Blds[c64 * 40 + q * 8 + p] = (bf16)v;
            }
            __syncthreads();
            const int m = w * 16;
            bf16x8 af = *(const bf16x8*)&Alds[(m + c) * 40 + g * 8];
#pragma unroll
            for (int j = 0; j < 4; ++j) {
                bf16x8 bv = *(const bf16x8*)&Blds[(j * 16 + c) * 40 + g * 8];
                acc[j] = __builtin_amdgcn_mfma_f32_16x16x32_bf16(af, bv, acc[j], 0, 0, 0);
            }
            __syncthreads();
        }
        const int m = w * 16;
#pragma unroll
        for (int j = 0; j < 4; ++j)
#pragma unroll
            for (int r = 0; r < 4; ++r)
                fproj[(size_t)(r0 + m + g * 4 + r) * HH + n0 + j * 16 + c] = (f16)acc[j][r];
    } else if (blk < 328) {
        int idx = (blk - 256) * 256 + tid;  // 0..18431
        int n = idx % NP;
        int rest = idx / NP;
        int kg = rest & 3;
        int k32 = rest >> 2;
        float v[8];
#pragma unroll
        for (int e = 0; e < 8; ++e) {
            int k = k32 * 32 + kg * 8 + e;
            v[e] = (n < NV) ? Wo[k * NV + n] * WOSCL : 0.f;
        }
        Wo_s[idx] = pack_fp8x8(v);
    } else {
        int u = blk - 328;  // 0..96
        for (int b = 0; b < BB; ++b) {
            int ctx = (u == 0) ? 0 : labels[b * UU + (u - 1)];
            const float* src = E + (size_t)ctx * HH;
            f16* dst = cemb + ((size_t)b * NU + u) * HH;
            for (int i = tid; i < HH; i += 256) dst[i] = (f16)src[i];
        }
    }
}

// ---- joint: logits = tanh(fproj[t]+cemb[u]) @ Wo  [fp8 MFMA, BK=64 K-loop]
// grid (388, B), block 512 = 8 waves (4 M-slots x 2 N-halves), wave tile 32x144.
// 8 barriers (2 k32 per iter). B-async issued BEFORE the MFMA phase (full
// flight before the barrier drain). A staging: thread stages (row, kg) and
// (row, kg+4) — second task is pure immediate offsets, no extra registers.
__global__ __launch_bounds__(512, 4) void k_joint(
    const f16* __restrict__ fproj, const f16* __restrict__ cemb,
    const long* __restrict__ Wo_s, const int* __restrict__ labels,
    const int* __restrict__ num_frames, float* __restrict__ cl_arr) {
    __shared__ long A_s8[2][8 * 130];  // 2 x 8 kg-planes x 130 longs (bank rot)
    __shared__ long B_s8[2][2304];     // 2 x 18432 B; [s][kg][n] longs
    __shared__ float red[6 * 128];     // cross-wave LSE combine

    const int tid = threadIdx.x;
    const int b = blockIdx.y;
    const int r0 = blockIdx.x * 128;
    const int nf = num_frames[b];
    if (r0 / NU >= nf) return;  // whole tile beyond active frames: outputs unused

    const int lane = tid & 63, w = tid >> 6;
    const int wm = w & 3, wn = w >> 2;
    const int c = lane & 15, g = lane >> 4;

    // A-staging: thread owns (row = tid>>2, kg = tid&3) and (row, kg+4).
    const int arow = tid >> 2, akg = tid & 3;
    const int gr = r0 + arow;
    const int at = gr / NU, au = gr - at * NU;
    const f16* pf = fproj + ((size_t)(b * TT + at)) * HH + akg * 8;
    const f16* pc = cemb + ((size_t)(b * NU + au)) * HH + akg * 8;
    const int sdst8 = akg * 130 + arow;  // second task: +520 (4 planes)
    const char* wsrcB = (const char*)Wo_s + lane * 16;

    f32x4 acc[2][9];
#pragma unroll
    for (int mt = 0; mt < 2; ++mt)
#pragma unroll
        for (int j = 0; j < 9; ++j) acc[mt][j] = (f32x4){0.f, 0.f, 0.f, 0.f};

    const int aB0 = g * 130 + wm * 32 + c;       // s=1: +520
    const int bB0 = g * 288 + wn * 144 + c;      // s=1: +1152

    // ---- prologue: stage k-chunk 0 (k=0..63) into buffer 0 ----
    {
        for (int ch = w; ch < 18; ch += 8)
            async_copy16(wsrcB + ch * 1024, (char*)&B_s8[0][0] + ch * 1024 + lane * 16);
        f16x8 fv0 = *(const f16x8*)pf;
        f16x8 cv0 = *(const f16x8*)pc;
        f16x8 fv1 = *(const f16x8*)(pf + 32);
        f16x8 cv1 = *(const f16x8*)(pc + 32);
        A_s8[0][sdst8] = tanh_pack8(fv0, cv0);
        A_s8[0][sdst8 + 520] = tanh_pack8(fv1, cv1);
        __syncthreads();
    }

    // ---- main loop: one barrier per 64-k chunk ----
    for (int i = 0; i < 8; ++i) {
        const int cur = i & 1, nxt = cur ^ 1;
        // B async for i+1 FIRST: flies through the whole MFMA+staging phase
        if (i < 7) {
            const char* wk = wsrcB + (size_t)(i + 1) * 18432;
            for (int ch = w; ch < 18; ch += 8)
                async_copy16(wk + ch * 1024, (char*)&B_s8[nxt][0] + ch * 1024 + lane * 16);
        }
        // MFMA over the two k32 sub-steps of buffer [cur]
#pragma unroll
        for (int s = 0; s < 2; ++s) {
            long af0 = A_s8[cur][aB0 + s * 520];
            long af1 = A_s8[cur][aB0 + s * 520 + 16];
#pragma unroll
            for (int j = 0; j < 9; ++j) {
                long bv = B_s8[cur][bB0 + s * 1152 + j * 16];
                acc[0][j] = __builtin_amdgcn_mfma_f32_16x16x32_fp8_fp8(af0, bv, acc[0][j], 0, 0, 0);
                acc[1][j] = __builtin_amdgcn_mfma_f32_16x16x32_fp8_fp8(af1, bv, acc[1][j], 0, 0, 0);
            }
        }
        // A staging for i+1: both load-pairs issued before first tanh
        if (i < 7) {
            const int kt = (i + 1) * 64;
            f16x8 fv0 = *(const f16x8*)(pf + kt);
            f16x8 cv0 = *(const f16x8*)(pc + kt);
            f16x8 fv1 = *(const f16x8*)(pf + kt + 32);
            f16x8 cv1 = *(const f16x8*)(pc + kt + 32);
            A_s8[nxt][sdst8] = tanh_pack8(fv0, cv0);
            A_s8[nxt][sdst8 + 520] = tanh_pack8(fv1, cv1);
        }
        __syncthreads();
    }

    // undo the Wo x64 pre-scale before LSE
#pragma unroll
    for (int mt = 0; mt < 2; ++mt)
#pragma unroll
        for (int j = 0; j < 9; ++j) acc[mt][j] = acc[mt][j] * INVWOSCL;

    // epilogue: per-wave partial lse over owned 144 cols, cross-wave combine in LDS
    float* pmax0 = red;
    float* pmax1 = red + 128;
    float* psum0 = red + 256;
    float* psum1 = red + 384;
    float* pblank = red + 512;
    float* plex = red + 640;

#pragma unroll
    for (int mt = 0; mt < 2; ++mt) {
#pragma unroll
        for (int r = 0; r < 4; ++r) {
            int row_in = wm * 32 + mt * 16 + g * 4 + r;
            int grr = r0 + row_in;
            int u = grr - (grr / NU) * NU;

            float mx = NEG_INF;
#pragma unroll
            for (int j = 0; j < 9; ++j) {
                int col = wn * 144 + j * 16 + c;
                if (col < NV) mx = fmaxf(mx, acc[mt][j][r]);
            }
#pragma unroll
            for (int s = 1; s < 16; s <<= 1) mx = fmaxf(mx, __shfl_xor(mx, s));
            float sum = 0.f;
#pragma unroll
            for (int j = 0; j < 9; ++j) {
                int col = wn * 144 + j * 16 + c;
                if (col < NV) sum += __expf(acc[mt][j][r] - mx);
            }
#pragma unroll
            for (int s = 1; s < 16; s <<= 1) sum += __shfl_xor(sum, s);

            int L = (u < UU) ? labels[b * UU + u] : -1;  // 1..256 or -1
            int lc = L - wn * 144;
            bool own = (lc >= 0) && (lc < 144);
            int src = (lane & 48) | (lc & 15);
            int jl = lc >> 4;
            float lexv = 0.f;
#pragma unroll
            for (int j = 0; j < 9; ++j) {
                float cand = __shfl(acc[mt][j][r], src);
                if (j == jl) lexv = cand;
            }
            float blankv = __shfl(acc[mt][0][r], lane & 48);  // col 0 (valid for wn==0)

            if (c == 0) {
                if (wn == 0) {
                    pmax0[row_in] = mx;
                    psum0[row_in] = sum;
                    pblank[row_in] = blankv;
                } else {
                    pmax1[row_in] = mx;
                    psum1[row_in] = sum;
                }
                if (own) plex[row_in] = lexv;
            }
        }
    }
    __syncthreads();
    if (tid < 128) {
        int grr = r0 + tid;
        int t = grr / NU, u = grr - t * NU;
        float m0 = pmax0[tid], m1 = pmax1[tid];
        float mx = fmaxf(m0, m1);
        float s = psum0[tid] * __expf(m0 - mx) + psum1[tid] * __expf(m1 - mx);
        float lse = mx + __logf(s);
        float2 v;
        v.x = pblank[tid] - lse;
        v.y = (u < UU) ? (plex[tid] - lse) : 0.f;
        *(float2*)&cl_arr[(((size_t)b * TT + t) * NU + u) * 2] = v;
    }
}

// ---- parallel depth-4 compaction: grid (NG, BB), block 128 (one thread per u).
__global__ __launch_bounds__(128) void k_compact(
    const float* __restrict__ cl, const int* __restrict__ num_frames,
    float* __restrict__ Dg) {
    const int g = blockIdx.x;
    const int b = blockIdx.y;
    const int u = threadIdx.x;
    if (u >= NU) return;
    const int nf = num_frames[b];
    const float2* P = (const float2*)(cl + (size_t)b * TT * NU * 2);

    auto fetch = [&](int t, int uu, float& bb, float& ll) {
        if (uu <= UU) {
            float2 z = P[t * NU + uu];
            bool act = t < nf;
            bb = act ? z.x * LOG2E : 0.f;
            ll = (act && uu < UU) ? z.y * LOG2E : NEG_INF;
        } else {
            bb = NEG_INF;
            ll = NEG_INF;
        }
    };

    const int t0 = g * 4;
    float b0, l0, b1u, l1u, b1u1, l1u1;
    fetch(t0, u, b0, l0);
    fetch(t0 + 1, u, b1u, l1u);
    fetch(t0 + 1, u + 1, b1u1, l1u1);
    float A0 = b0 + b1u;
    float A1 = lae2(l0 + b1u1, b0 + l1u);
    float A2 = l0 + l1u1;
    float B0[3], B1[3], B2[3];
#pragma unroll
    for (int j = 0; j < 3; ++j) {
        float b2v, l2v, b3v, l3v, b3n, l3n;
        fetch(t0 + 2, u + j, b2v, l2v);
        fetch(t0 + 3, u + j, b3v, l3v);
        fetch(t0 + 3, u + j + 1, b3n, l3n);
        B0[j] = b2v + b3v;
        B1[j] = lae2(l2v + b3n, b2v + l3v);
        B2[j] = l2v + l3n;
    }
    float* d = Dg + ((size_t)b * NG + g) * GSTRIDE;
    d[u] = A0 + B0[0];
    d[104 + u] = lae2(A1 + B0[1], A0 + B1[0]);
    d[208 + u] = lse3_2(A2 + B0[2], A1 + B1[1], A0 + B2[0]);
    d[312 + u] = lae2(A2 + B1[2], A1 + B2[1]);
    d[416 + u] = A2 + B2[2];
}

// ---- serial chain: 1 wave per batch, 128 banded-lse5 steps, 8-deep reg ring.
__global__ __launch_bounds__(64) void k_dpser(
    const float* __restrict__ Dg, const int* __restrict__ num_labels,
    float* __restrict__ out) {
    const int b = blockIdx.x;
    const int lane = threadIdx.x;
    const float* D = Dg + (size_t)b * NG * GSTRIDE;
    const int lo_u = lane;
    const int hi_u = 64 + ((lane < 33) ? lane : 0);

    float a_lo = (lane == 0) ? 0.f : NEG_INF;  // alpha[u=lane] (base-2)
    float a_hi = NEG_INF;                      // alpha[u=64+lane], lane<33

    constexpr int R = 8;
    float blo[R][5], bhi[R][5];
#pragma unroll
    for (int g = 0; g < R; ++g)
#pragma unroll
        for (int k = 0; k < 5; ++k) {
            blo[g][k] = D[g * GSTRIDE + k * 104 + lo_u];
            bhi[g][k] = D[g * GSTRIDE + k * 104 + hi_u];
        }

#pragma unroll 8
    for (int g = 0; g < NG; ++g) {
        const int slot = g & (R - 1);
        float el[5], eh[5];
#pragma unroll
        for (int k = 0; k < 5; ++k) {
            el[k] = a_lo + blo[slot][k];
            eh[k] = a_hi + bhi[slot][k];
        }
        const int gp = g + R;
        if (gp < NG) {
#pragma unroll
            for (int k = 0; k < 5; ++k) {
                blo[slot][k] = D[gp * GSTRIDE + k * 104 + lo_u];
                bhi[slot][k] = D[gp * GSTRIDE + k * 104 + hi_u];
            }
        }
        float ml[5], mh[5];
        ml[0] = el[0];
        mh[0] = eh[0];
#pragma unroll
        for (int k = 1; k < 5; ++k) {
            float su = __shfl_up(el[k], k);
            ml[k] = (lane >= k) ? su : NEG_INF;
            float sh = __shfl_up(eh[k], k);
            float xl = __shfl(el[k], 64 - k + lane);  // lo lanes 63..64-k
            mh[k] = (lane >= k) ? sh : xl;
        }
        a_lo = lse5_2(ml[0], ml[1], ml[2], ml[3], ml[4]);
        float nh = lse5_2(mh[0], mh[1], mh[2], mh[3], mh[4]);
        if (lane < 33) a_hi = nh;
    }

    const int nl = num_labels[b];
    float res = (nl < 64) ? __shfl(a_lo, nl) : __shfl(a_hi, nl - 64);
    if (lane == 0) out[b] = -res * LN2;  // back to natural-log domain
}

extern "C" void kernel_launch(void* const* d_in, const int* in_sizes, int n_in,
                              void* d_out, int out_size, void* d_ws, size_t ws_size,
                              hipStream_t stream) {
    const float* frames = (const float*)d_in[0];
    const int* num_frames = (const int*)d_in[1];
    const int* labels = (const int*)d_in[2];
    const int* num_labels = (const int*)d_in[3];
    const float* Wf = (const float*)d_in[4];
    const float* E = (const float*)d_in[5];
    const float* Wo = (const float*)d_in[6];
    float* out = (float*)d_out;

    char* ws = (char*)d_ws;
    size_t off = 0;
    long* Wo_s = (long*)(ws + off); off += (size_t)18432 * 8;                 // 144 KiB
    f16* cemb = (f16*)(ws + off); off += (size_t)BB * NU * HH * 2;            // 388 KiB
    off = (off + 255) & ~(size_t)255;
    f16* fproj = (f16*)(ws + off); off += (size_t)BB * TT * HH * 2;           // 2 MiB
    off = (off + 255) & ~(size_t)255;
    float* cl_arr = (float*)(ws + off); off += (size_t)BB * TT * NU * 2 * 4;  // 1.52 MiB
    off = (off + 255) & ~(size_t)255;
    float* Dg = (float*)(ws + off); off += (size_t)BB * NG * GSTRIDE * 4;     // 1.02 MiB

    hipLaunchKernelGGL(k_front, dim3(425), dim3(256), 0, stream,
                       frames, Wf, Wo, E, labels, fproj, Wo_s, cemb);
    hipLaunchKernelGGL(k_joint, dim3((TT * NU) / 128, BB), dim3(512), 0, stream,
                       fproj, cemb, Wo_s, labels, num_frames, cl_arr);
    hipLaunchKernelGGL(k_compact, dim3(NG, BB), dim3(128), 0, stream,
                       cl_arr, num_frames, Dg);
    hipLaunchKernelGGL(k_dpser, dim3(BB), dim3(64), 0, stream,
                       Dg, num_labels, out);
}